// Round 3
// baseline (124.900 us; speedup 1.0000x reference)
//
#include <hip/hip_runtime.h>

// Problem constants
#define B_    4
#define S_    2048
#define DM_   1024
#define DK_   64
#define SCALE_ 0.03125f   // 1024^-0.5  (reference scales by d_model^-0.5, not d_k)

typedef float        f32x4  __attribute__((ext_vector_type(4)));
typedef short        short8 __attribute__((ext_vector_type(8)));
typedef float        fltx4  __attribute__((ext_vector_type(4)));
typedef unsigned int uint2v __attribute__((ext_vector_type(2)));
typedef unsigned int uint4v __attribute__((ext_vector_type(4)));

// fp32 -> bf16, round-to-nearest-even
static __device__ __forceinline__ unsigned short f2bf(float f) {
  unsigned u = __float_as_uint(f);
  u += 0x7fffu + ((u >> 16) & 1u);
  return (unsigned short)(u >> 16);
}
static __device__ __forceinline__ uint2v pack4(float a, float b, float c, float d) {
  uint2v r;
  r.x = (unsigned)f2bf(a) | ((unsigned)f2bf(b) << 16);
  r.y = (unsigned)f2bf(c) | ((unsigned)f2bf(d) << 16);
  return r;
}

// ---------------------------------------------------------------------------
// Kernel 0: detect mask element width (int32 of {0,1} vs byte-packed bools).
// Verified working in R2 (maskpack round-trip T3 passed).
// ---------------------------------------------------------------------------
__global__ void detect_kernel(const unsigned int* __restrict__ m, unsigned int* __restrict__ flag) {
  unsigned v = m[threadIdx.x];
  unsigned long long bad = __ballot(v > 1u);
  if (threadIdx.x == 0) flag[0] = (bad != 0ull) ? 1u : 0u;
}

// ---------------------------------------------------------------------------
// Kernel 1: pack mask to 1 bit/element (2 MB total, L2-hot for attn).
// Word w holds elements [32w, 32w+32), bit j = element 32w+j (nonzero -> 1).
// R2 selftest T3: verified round-trip vs raw mask.
// ---------------------------------------------------------------------------
__global__ __launch_bounds__(256) void maskpack_kernel(const unsigned char* __restrict__ mb,
                                                       const unsigned int* __restrict__ mi,
                                                       const unsigned int* __restrict__ flag,
                                                       unsigned int* __restrict__ mp) {
  const int w = blockIdx.x * 256 + threadIdx.x;
  unsigned out = 0;
  if (flag[0]) {
    const uint4v* p = reinterpret_cast<const uint4v*>(mb + (size_t)w * 32);
    uint4v a = p[0], b = p[1];
    unsigned ws0[8];
    ws0[0]=a.x; ws0[1]=a.y; ws0[2]=a.z; ws0[3]=a.w; ws0[4]=b.x; ws0[5]=b.y; ws0[6]=b.z; ws0[7]=b.w;
#pragma unroll
    for (int i = 0; i < 8; ++i) {
      unsigned v = ws0[i];
      out |= ((v & 0x000000ffu) ? 1u : 0u) << (i * 4 + 0);
      out |= ((v & 0x0000ff00u) ? 1u : 0u) << (i * 4 + 1);
      out |= ((v & 0x00ff0000u) ? 1u : 0u) << (i * 4 + 2);
      out |= ((v & 0xff000000u) ? 1u : 0u) << (i * 4 + 3);
    }
  } else {
    const uint4v* p = reinterpret_cast<const uint4v*>(mi + (size_t)w * 32);
#pragma unroll
    for (int i = 0; i < 8; ++i) {
      uint4v a = p[i];
      out |= (a.x ? 1u : 0u) << (i * 4 + 0);
      out |= (a.y ? 1u : 0u) << (i * 4 + 1);
      out |= (a.z ? 1u : 0u) << (i * 4 + 2);
      out |= (a.w ? 1u : 0u) << (i * 4 + 3);
    }
  }
  mp[w] = out;
}

// ---------------------------------------------------------------------------
// Kernel 2: projections. 64-row tiles, bf16 MFMA, padded LDS [64][72].
// R2 selftest T4: verified vs fp32 reference dot products (192 samples).
// ---------------------------------------------------------------------------
__global__ __launch_bounds__(256) void proj_kernel(
    const float* __restrict__ xq, const float* __restrict__ xk, const float* __restrict__ xv,
    const float* __restrict__ wq, const float* __restrict__ wk, const float* __restrict__ wv,
    unsigned short* __restrict__ Qp, unsigned short* __restrict__ Kp, unsigned short* __restrict__ Vt)
{
  const int which = blockIdx.y;
  const float* __restrict__ x = (which == 0) ? xq : (which == 1) ? xk : xv;
  const float* __restrict__ w = (which == 0) ? wq : (which == 1) ? wk : wv;
  const int row0 = blockIdx.x * 64;

  __shared__ __align__(16) unsigned short Xs[64][72];
  __shared__ __align__(16) unsigned short Ws[64][72];

  const int tid  = threadIdx.x;
  const int lane = tid & 63;
  const int wid  = tid >> 6;
  const int g    = lane >> 4, r16 = lane & 15;
  const int wr   = wid >> 1,  wc  = wid & 1;
  const int trow = tid >> 4,  tcol = (tid & 15) << 2;

  f32x4 acc[4];
#pragma unroll
  for (int i = 0; i < 4; ++i) { acc[i].x = 0.f; acc[i].y = 0.f; acc[i].z = 0.f; acc[i].w = 0.f; }

  for (int kc = 0; kc < 16; ++kc) {
    const int kbase = kc * 64;
#pragma unroll
    for (int i = 0; i < 4; ++i) {
      int r = i * 16 + trow;
      fltx4 vx = *reinterpret_cast<const fltx4*>(x + (size_t)(row0 + r) * DM_ + kbase + tcol);
      *reinterpret_cast<uint2v*>(&Xs[r][tcol]) = pack4(vx.x, vx.y, vx.z, vx.w);
      fltx4 vw = *reinterpret_cast<const fltx4*>(w + (size_t)r * DM_ + kbase + tcol);
      *reinterpret_cast<uint2v*>(&Ws[r][tcol]) = pack4(vw.x, vw.y, vw.z, vw.w);
    }
    __syncthreads();

    if (which < 2) {
#pragma unroll
      for (int k2 = 0; k2 < 2; ++k2) {
        short8 a0 = *reinterpret_cast<const short8*>(&Ws[wr * 32 + r16     ][k2 * 32 + g * 8]);
        short8 a1 = *reinterpret_cast<const short8*>(&Ws[wr * 32 + 16 + r16][k2 * 32 + g * 8]);
#pragma unroll
        for (int nf = 0; nf < 2; ++nf) {
          short8 bx = *reinterpret_cast<const short8*>(&Xs[wc * 32 + nf * 16 + r16][k2 * 32 + g * 8]);
          acc[nf]     = __builtin_amdgcn_mfma_f32_16x16x32_bf16(a0, bx, acc[nf], 0, 0, 0);
          acc[2 + nf] = __builtin_amdgcn_mfma_f32_16x16x32_bf16(a1, bx, acc[2 + nf], 0, 0, 0);
        }
      }
    } else {
#pragma unroll
      for (int k2 = 0; k2 < 2; ++k2) {
        short8 b0 = *reinterpret_cast<const short8*>(&Ws[wc * 32 + r16     ][k2 * 32 + g * 8]);
        short8 b1 = *reinterpret_cast<const short8*>(&Ws[wc * 32 + 16 + r16][k2 * 32 + g * 8]);
#pragma unroll
        for (int mf = 0; mf < 2; ++mf) {
          short8 ax = *reinterpret_cast<const short8*>(&Xs[wr * 32 + mf * 16 + r16][k2 * 32 + g * 8]);
          acc[mf * 2]     = __builtin_amdgcn_mfma_f32_16x16x32_bf16(ax, b0, acc[mf * 2], 0, 0, 0);
          acc[mf * 2 + 1] = __builtin_amdgcn_mfma_f32_16x16x32_bf16(ax, b1, acc[mf * 2 + 1], 0, 0, 0);
        }
      }
    }
    __syncthreads();
  }

  if (which < 2) {
    unsigned short* __restrict__ dst = (which == 0) ? Qp : Kp;
#pragma unroll
    for (int mf = 0; mf < 2; ++mf)
#pragma unroll
      for (int nf = 0; nf < 2; ++nf) {
        f32x4 a = acc[mf * 2 + nf];
        int row_out = row0 + wc * 32 + nf * 16 + r16;
        int n0      = wr * 32 + mf * 16 + g * 4;
        *reinterpret_cast<uint2v*>(dst + (size_t)row_out * DK_ + n0) = pack4(a.x, a.y, a.z, a.w);
      }
  } else {
#pragma unroll
    for (int mf = 0; mf < 2; ++mf)
#pragma unroll
      for (int nf = 0; nf < 2; ++nf) {
        f32x4 a   = acc[mf * 2 + nf];
        int srow  = row0 + wr * 32 + mf * 16 + g * 4;
        int bb    = srow >> 11;
        int sin   = srow & 2047;
        int col   = wc * 32 + nf * 16 + r16;
        *reinterpret_cast<uint2v*>(Vt + (size_t)(bb * DK_ + col) * S_ + sin) = pack4(a.x, a.y, a.z, a.w);
      }
  }
}

// ---------------------------------------------------------------------------
// Kernel 3: flash attention. 512 blocks x 1 wave; 16 q rows per wave.
// P routed through LDS as Pq[q][s] (plain writes + contiguous short8 reads).
// All building blocks verified by R2 selftests (T1 MFMA layout, T3 mask,
// T4 projections).
// ---------------------------------------------------------------------------
__global__ __launch_bounds__(64) void attn_kernel(
    const unsigned short* __restrict__ Qp, const unsigned short* __restrict__ Kp,
    const unsigned short* __restrict__ Vt, const unsigned int* __restrict__ mp,
    float* __restrict__ out)
{
  const int lane = threadIdx.x;
  const int g = lane >> 4, r16 = lane & 15;
  const int qt = blockIdx.x & 127;
  const int b  = blockIdx.x >> 7;
  const int q0 = qt * 16;

  __shared__ __align__(16) unsigned short Kt[64][72];
  __shared__ __align__(16) unsigned short Vs[64][72];
  __shared__ __align__(16) unsigned short Pq[16][72];   // P[q][s-local]

  short8 aq0, aq1;
  {
    const unsigned short* qrow = Qp + (size_t)(b * S_ + q0 + r16) * DK_ + g * 8;
    aq0 = *reinterpret_cast<const short8*>(qrow);
    aq1 = *reinterpret_cast<const short8*>(qrow + 32);
  }

  float mrun[4], lsum[4], corr[4];
  f32x4 acc[4];
#pragma unroll
  for (int j = 0; j < 4; ++j) { mrun[j] = -3.0e38f; lsum[j] = 0.f; }
#pragma unroll
  for (int nf = 0; nf < 4; ++nf) { acc[nf].x = 0.f; acc[nf].y = 0.f; acc[nf].z = 0.f; acc[nf].w = 0.f; }

  const int srow_stage = lane >> 3, sgran = lane & 7;

  for (int st = 0; st < 32; ++st) {
    const int s0 = st * 64;
#pragma unroll
    for (int i = 0; i < 8; ++i) {
      int r = i * 8 + srow_stage;
      uint4v kv = *reinterpret_cast<const uint4v*>(Kp + (size_t)(b * S_ + s0 + r) * DK_ + sgran * 8);
      *reinterpret_cast<uint4v*>(&Kt[r][sgran * 8]) = kv;
      uint4v vv = *reinterpret_cast<const uint4v*>(Vt + (size_t)(b * DK_ + r) * S_ + s0 + sgran * 8);
      *reinterpret_cast<uint4v*>(&Vs[r][sgran * 8]) = vv;
    }
    unsigned long long mw[4];
#pragma unroll
    for (int j = 0; j < 4; ++j) {
      size_t widx = ((size_t)(b * S_ + q0 + g * 4 + j) * S_ + s0) >> 5;
      mw[j] = *reinterpret_cast<const unsigned long long*>(mp + widx);
    }
    __syncthreads();

    // QK^T: frag nf covers s = s0 + nf*16 + r16, reg j -> q = g*4 + j
    f32x4 sc[4];
#pragma unroll
    for (int nf = 0; nf < 4; ++nf) { sc[nf].x = 0.f; sc[nf].y = 0.f; sc[nf].z = 0.f; sc[nf].w = 0.f; }
#pragma unroll
    for (int nf = 0; nf < 4; ++nf) {
      short8 bk0 = *reinterpret_cast<const short8*>(&Kt[nf * 16 + r16][g * 8]);
      short8 bk1 = *reinterpret_cast<const short8*>(&Kt[nf * 16 + r16][32 + g * 8]);
      sc[nf] = __builtin_amdgcn_mfma_f32_16x16x32_bf16(aq0, bk0, sc[nf], 0, 0, 0);
      sc[nf] = __builtin_amdgcn_mfma_f32_16x16x32_bf16(aq1, bk1, sc[nf], 0, 0, 0);
    }
    // scale + masked-fill (reference: where(mask, 1e-9, scores))
#pragma unroll
    for (int nf = 0; nf < 4; ++nf)
#pragma unroll
      for (int j = 0; j < 4; ++j) {
        float v = sc[nf][j] * SCALE_;
        sc[nf][j] = ((mw[j] >> (nf * 16 + r16)) & 1ull) ? 1e-9f : v;
      }
    // online softmax (row q = g*4+j lives on the 16 lanes of group g)
#pragma unroll
    for (int j = 0; j < 4; ++j) {
      float tm = fmaxf(fmaxf(sc[0][j], sc[1][j]), fmaxf(sc[2][j], sc[3][j]));
#pragma unroll
      for (int off = 1; off < 16; off <<= 1) tm = fmaxf(tm, __shfl_xor(tm, off));
      float mn = fmaxf(mrun[j], tm);
      corr[j] = __expf(mrun[j] - mn);
      mrun[j] = mn;
    }
#pragma unroll
    for (int nf = 0; nf < 4; ++nf)
#pragma unroll
      for (int j = 0; j < 4; ++j)
        sc[nf][j] = __expf(sc[nf][j] - mrun[j]);
#pragma unroll
    for (int j = 0; j < 4; ++j) {
      float rs = (sc[0][j] + sc[1][j]) + (sc[2][j] + sc[3][j]);
#pragma unroll
      for (int off = 1; off < 16; off <<= 1) rs += __shfl_xor(rs, off);
      lsum[j] = lsum[j] * corr[j] + rs;
    }
#pragma unroll
    for (int nf = 0; nf < 4; ++nf) {
      acc[nf].x *= corr[0]; acc[nf].y *= corr[1]; acc[nf].z *= corr[2]; acc[nf].w *= corr[3];
    }
    // P -> LDS [q][s] (scalar b16 writes; vectorize next round if hot)
#pragma unroll
    for (int nf = 0; nf < 4; ++nf)
#pragma unroll
      for (int j = 0; j < 4; ++j)
        Pq[g * 4 + j][nf * 16 + r16] = f2bf(sc[nf][j]);
    asm volatile("s_waitcnt lgkmcnt(0)" ::: "memory");

    // PV: A = P rows (contiguous), B = V^T rows
#pragma unroll
    for (int k2 = 0; k2 < 2; ++k2) {
      short8 pa = *reinterpret_cast<const short8*>(&Pq[r16][k2 * 32 + g * 8]);
#pragma unroll
      for (int nf = 0; nf < 4; ++nf) {
        short8 bv = *reinterpret_cast<const short8*>(&Vs[nf * 16 + r16][k2 * 32 + g * 8]);
        acc[nf] = __builtin_amdgcn_mfma_f32_16x16x32_bf16(pa, bv, acc[nf], 0, 0, 0);
      }
    }
    __syncthreads();
  }

  // epilogue: out[q][dk] = acc / l
#pragma unroll
  for (int nf = 0; nf < 4; ++nf)
#pragma unroll
    for (int j = 0; j < 4; ++j)
      out[(size_t)(b * S_ + q0 + g * 4 + j) * DK_ + nf * 16 + r16] = acc[nf][j] / lsum[j];
}

// ---------------------------------------------------------------------------
extern "C" void kernel_launch(void* const* d_in, const int* in_sizes, int n_in,
                              void* d_out, int out_size, void* d_ws, size_t ws_size,
                              hipStream_t stream) {
  const float* q  = (const float*)d_in[0];
  const float* k  = (const float*)d_in[1];
  const float* v  = (const float*)d_in[2];
  const void*  mk = d_in[3];
  const float* wq = (const float*)d_in[4];
  const float* wk = (const float*)d_in[5];
  const float* wv = (const float*)d_in[6];

  char* ws = (char*)d_ws;
  unsigned short* Qp   = (unsigned short*)(ws);                    // 1 MB
  unsigned short* Kp   = (unsigned short*)(ws + (1u << 20));       // 1 MB
  unsigned short* Vt   = (unsigned short*)(ws + (2u << 20));       // 1 MB  [b][dk][s]
  unsigned int*   mp   = (unsigned int*)  (ws + (3u << 20));       // 2 MB packed mask
  unsigned int*   flag = (unsigned int*)  (ws + (5u << 20));       // flag[0]=dtype

  detect_kernel<<<1, 64, 0, stream>>>((const unsigned int*)mk, flag);
  maskpack_kernel<<<2048, 256, 0, stream>>>((const unsigned char*)mk, (const unsigned int*)mk, flag, mp);
  proj_kernel<<<dim3(128, 3), 256, 0, stream>>>(q, k, v, wq, wk, wv, Qp, Kp, Vt);
  attn_kernel<<<512, 64, 0, stream>>>(Qp, Kp, Vt, mp, (float*)d_out);
}

// Round 4
// 115.259 us; speedup vs baseline: 1.0837x; 1.0837x over previous
//
#include <hip/hip_runtime.h>

// Problem constants
#define B_    4
#define S_    2048
#define DM_   1024
#define DK_   64
#define SCALE_ 0.03125f   // 1024^-0.5  (reference scales by d_model^-0.5, not d_k)

typedef float        f32x4  __attribute__((ext_vector_type(4)));
typedef float        float8 __attribute__((ext_vector_type(8)));
typedef short        short8 __attribute__((ext_vector_type(8)));
typedef float        fltx4  __attribute__((ext_vector_type(4)));
typedef unsigned int uint2v __attribute__((ext_vector_type(2)));
typedef unsigned int uint4v __attribute__((ext_vector_type(4)));

// fp32 -> bf16, round-to-nearest-even
static __device__ __forceinline__ unsigned short f2bf(float f) {
  unsigned u = __float_as_uint(f);
  u += 0x7fffu + ((u >> 16) & 1u);
  return (unsigned short)(u >> 16);
}
static __device__ __forceinline__ uint2v pack4(float a, float b, float c, float d) {
  uint2v r;
  r.x = (unsigned)f2bf(a) | ((unsigned)f2bf(b) << 16);
  r.y = (unsigned)f2bf(c) | ((unsigned)f2bf(d) << 16);
  return r;
}
static __device__ __forceinline__ short8 cvt8(float8 v) {
  short8 r;
#pragma unroll
  for (int i = 0; i < 8; ++i) r[i] = (short)f2bf(v[i]);
  return r;
}

// ---------------------------------------------------------------------------
// Kernel 0: detect mask element width (int32 of {0,1} vs byte-packed bools).
// Verified in R2 (T3 round-trip passed under int32 mode).
// ---------------------------------------------------------------------------
__global__ void detect_kernel(const unsigned int* __restrict__ m, unsigned int* __restrict__ flag) {
  unsigned v = m[threadIdx.x];
  unsigned long long bad = __ballot(v > 1u);
  if (threadIdx.x == 0) flag[0] = (bad != 0ull) ? 1u : 0u;
}

// ---------------------------------------------------------------------------
// Kernel W: convert the 3 weight matrices to bf16 once.
// Wb layout: [which][n=64][k=1024] row-major (same as torch [d_k][d_model]).
// ---------------------------------------------------------------------------
__global__ __launch_bounds__(256) void wconv_kernel(
    const float* __restrict__ wq, const float* __restrict__ wk, const float* __restrict__ wv,
    unsigned short* __restrict__ Wb)
{
  const int idx   = blockIdx.x * 256 + threadIdx.x;   // 24576 threads, 8 elems each
  const int which = idx >> 13;                        // 8192 threads per matrix
  const int e     = idx & 8191;
  const float* __restrict__ w = (which == 0) ? wq : (which == 1) ? wk : wv;
  fltx4 v0 = *reinterpret_cast<const fltx4*>(w + (size_t)e * 8);
  fltx4 v1 = *reinterpret_cast<const fltx4*>(w + (size_t)e * 8 + 4);
  uint4v o;
  o.x = (unsigned)f2bf(v0.x) | ((unsigned)f2bf(v0.y) << 16);
  o.y = (unsigned)f2bf(v0.z) | ((unsigned)f2bf(v0.w) << 16);
  o.z = (unsigned)f2bf(v1.x) | ((unsigned)f2bf(v1.y) << 16);
  o.w = (unsigned)f2bf(v1.z) | ((unsigned)f2bf(v1.w) << 16);
  *reinterpret_cast<uint4v*>(Wb + (size_t)which * 65536 + (size_t)e * 8) = o;
}

// ---------------------------------------------------------------------------
// Kernel 1: pack mask to 1 bit/element (2 MB, L2-hot for attn).
// R2 selftest T3: verified round-trip vs raw mask.
// ---------------------------------------------------------------------------
__global__ __launch_bounds__(256) void maskpack_kernel(const unsigned char* __restrict__ mb,
                                                       const unsigned int* __restrict__ mi,
                                                       const unsigned int* __restrict__ flag,
                                                       unsigned int* __restrict__ mp) {
  const int w = blockIdx.x * 256 + threadIdx.x;
  unsigned out = 0;
  if (flag[0]) {
    const uint4v* p = reinterpret_cast<const uint4v*>(mb + (size_t)w * 32);
    uint4v a = p[0], b = p[1];
    unsigned ws0[8];
    ws0[0]=a.x; ws0[1]=a.y; ws0[2]=a.z; ws0[3]=a.w; ws0[4]=b.x; ws0[5]=b.y; ws0[6]=b.z; ws0[7]=b.w;
#pragma unroll
    for (int i = 0; i < 8; ++i) {
      unsigned v = ws0[i];
      out |= ((v & 0x000000ffu) ? 1u : 0u) << (i * 4 + 0);
      out |= ((v & 0x0000ff00u) ? 1u : 0u) << (i * 4 + 1);
      out |= ((v & 0x00ff0000u) ? 1u : 0u) << (i * 4 + 2);
      out |= ((v & 0xff000000u) ? 1u : 0u) << (i * 4 + 3);
    }
  } else {
    const uint4v* p = reinterpret_cast<const uint4v*>(mi + (size_t)w * 32);
#pragma unroll
    for (int i = 0; i < 8; ++i) {
      uint4v a = p[i];
      out |= (a.x ? 1u : 0u) << (i * 4 + 0);
      out |= (a.y ? 1u : 0u) << (i * 4 + 1);
      out |= (a.z ? 1u : 0u) << (i * 4 + 2);
      out |= (a.w ? 1u : 0u) << (i * 4 + 3);
    }
  }
  mp[w] = out;
}

// ---------------------------------------------------------------------------
// Kernel 2 (REWRITE): barrier-free, LDS-free projection.
// 1 wave per 16 x-rows. A-frag straight from global fp32 (lane r16 = row,
// 32 B contiguous per lane); B-frags from bf16 Wb (L1/L2-hot, lane r16 = n).
// Fragment convention verified by R2 selftest T1. Two-stage register
// prefetch hides HBM latency; no __syncthreads anywhere.
//   D[m=g*4+j][n=nf*16+r16] = sum_k x[row0+m][k] * W[n][k]
// ---------------------------------------------------------------------------
__global__ __launch_bounds__(64) void proj2_kernel(
    const float* __restrict__ xq, const float* __restrict__ xk, const float* __restrict__ xv,
    const unsigned short* __restrict__ Wb,
    unsigned short* __restrict__ Qp, unsigned short* __restrict__ Kp, unsigned short* __restrict__ Vt)
{
  const int which = blockIdx.y;
  const float* __restrict__ x = (which == 0) ? xq : (which == 1) ? xk : xv;
  const int row0 = blockIdx.x * 16;
  const int lane = threadIdx.x, g = lane >> 4, r16 = lane & 15;

  const float* __restrict__ xrow = x + (size_t)(row0 + r16) * DM_ + g * 8;
  const unsigned short* __restrict__ wbase = Wb + (size_t)which * 65536 + g * 8;

  f32x4 acc[4];
#pragma unroll
  for (int i = 0; i < 4; ++i) { acc[i].x = 0.f; acc[i].y = 0.f; acc[i].z = 0.f; acc[i].w = 0.f; }

  float8 xa0, xa1;
  short8 wb0[4], wb1[4];

  // prefetch k-step 0
  xa0 = *reinterpret_cast<const float8*>(xrow);
#pragma unroll
  for (int nf = 0; nf < 4; ++nf)
    wb0[nf] = *reinterpret_cast<const short8*>(wbase + (size_t)(nf * 16 + r16) * DM_);

#pragma unroll 1
  for (int kc = 0; kc < 32; kc += 2) {
    // prefetch k-step kc+1 into buffer 1
    if (kc + 1 < 32) {
      xa1 = *reinterpret_cast<const float8*>(xrow + (kc + 1) * 32);
#pragma unroll
      for (int nf = 0; nf < 4; ++nf)
        wb1[nf] = *reinterpret_cast<const short8*>(wbase + (size_t)(nf * 16 + r16) * DM_ + (kc + 1) * 32);
    }
    {
      short8 a = cvt8(xa0);
#pragma unroll
      for (int nf = 0; nf < 4; ++nf)
        acc[nf] = __builtin_amdgcn_mfma_f32_16x16x32_bf16(a, wb0[nf], acc[nf], 0, 0, 0);
    }
    // prefetch k-step kc+2 into buffer 0
    if (kc + 2 < 32) {
      xa0 = *reinterpret_cast<const float8*>(xrow + (kc + 2) * 32);
#pragma unroll
      for (int nf = 0; nf < 4; ++nf)
        wb0[nf] = *reinterpret_cast<const short8*>(wbase + (size_t)(nf * 16 + r16) * DM_ + (kc + 2) * 32);
    }
    {
      short8 a = cvt8(xa1);
#pragma unroll
      for (int nf = 0; nf < 4; ++nf)
        acc[nf] = __builtin_amdgcn_mfma_f32_16x16x32_bf16(a, wb1[nf], acc[nf], 0, 0, 0);
    }
  }

  if (which < 2) {
    unsigned short* __restrict__ dst = (which == 0) ? Qp : Kp;
#pragma unroll
    for (int nf = 0; nf < 4; ++nf)
#pragma unroll
      for (int j = 0; j < 4; ++j)
        dst[(size_t)(row0 + g * 4 + j) * DK_ + nf * 16 + r16] = f2bf(acc[nf][j]);
  } else {
    const int grow = row0 + g * 4;
    const int bb = grow >> 11, sin = grow & 2047;
#pragma unroll
    for (int nf = 0; nf < 4; ++nf)
      *reinterpret_cast<uint2v*>(Vt + (size_t)(bb * DK_ + nf * 16 + r16) * S_ + sin) =
          pack4(acc[nf][0], acc[nf][1], acc[nf][2], acc[nf][3]);
  }
}

// ---------------------------------------------------------------------------
// Kernel 3: flash attention (UNCHANGED from R3 — verified passing).
// 512 blocks x 1 wave; 16 q rows per wave.
// ---------------------------------------------------------------------------
__global__ __launch_bounds__(64) void attn_kernel(
    const unsigned short* __restrict__ Qp, const unsigned short* __restrict__ Kp,
    const unsigned short* __restrict__ Vt, const unsigned int* __restrict__ mp,
    float* __restrict__ out)
{
  const int lane = threadIdx.x;
  const int g = lane >> 4, r16 = lane & 15;
  const int qt = blockIdx.x & 127;
  const int b  = blockIdx.x >> 7;
  const int q0 = qt * 16;

  __shared__ __align__(16) unsigned short Kt[64][72];
  __shared__ __align__(16) unsigned short Vs[64][72];
  __shared__ __align__(16) unsigned short Pq[16][72];   // P[q][s-local]

  short8 aq0, aq1;
  {
    const unsigned short* qrow = Qp + (size_t)(b * S_ + q0 + r16) * DK_ + g * 8;
    aq0 = *reinterpret_cast<const short8*>(qrow);
    aq1 = *reinterpret_cast<const short8*>(qrow + 32);
  }

  float mrun[4], lsum[4], corr[4];
  f32x4 acc[4];
#pragma unroll
  for (int j = 0; j < 4; ++j) { mrun[j] = -3.0e38f; lsum[j] = 0.f; }
#pragma unroll
  for (int nf = 0; nf < 4; ++nf) { acc[nf].x = 0.f; acc[nf].y = 0.f; acc[nf].z = 0.f; acc[nf].w = 0.f; }

  const int srow_stage = lane >> 3, sgran = lane & 7;

  for (int st = 0; st < 32; ++st) {
    const int s0 = st * 64;
#pragma unroll
    for (int i = 0; i < 8; ++i) {
      int r = i * 8 + srow_stage;
      uint4v kv = *reinterpret_cast<const uint4v*>(Kp + (size_t)(b * S_ + s0 + r) * DK_ + sgran * 8);
      *reinterpret_cast<uint4v*>(&Kt[r][sgran * 8]) = kv;
      uint4v vv = *reinterpret_cast<const uint4v*>(Vt + (size_t)(b * DK_ + r) * S_ + s0 + sgran * 8);
      *reinterpret_cast<uint4v*>(&Vs[r][sgran * 8]) = vv;
    }
    unsigned long long mw[4];
#pragma unroll
    for (int j = 0; j < 4; ++j) {
      size_t widx = ((size_t)(b * S_ + q0 + g * 4 + j) * S_ + s0) >> 5;
      mw[j] = *reinterpret_cast<const unsigned long long*>(mp + widx);
    }
    __syncthreads();

    // QK^T: frag nf covers s = s0 + nf*16 + r16, reg j -> q = g*4 + j
    f32x4 sc[4];
#pragma unroll
    for (int nf = 0; nf < 4; ++nf) { sc[nf].x = 0.f; sc[nf].y = 0.f; sc[nf].z = 0.f; sc[nf].w = 0.f; }
#pragma unroll
    for (int nf = 0; nf < 4; ++nf) {
      short8 bk0 = *reinterpret_cast<const short8*>(&Kt[nf * 16 + r16][g * 8]);
      short8 bk1 = *reinterpret_cast<const short8*>(&Kt[nf * 16 + r16][32 + g * 8]);
      sc[nf] = __builtin_amdgcn_mfma_f32_16x16x32_bf16(aq0, bk0, sc[nf], 0, 0, 0);
      sc[nf] = __builtin_amdgcn_mfma_f32_16x16x32_bf16(aq1, bk1, sc[nf], 0, 0, 0);
    }
    // scale + masked-fill (reference: where(mask, 1e-9, scores))
#pragma unroll
    for (int nf = 0; nf < 4; ++nf)
#pragma unroll
      for (int j = 0; j < 4; ++j) {
        float v = sc[nf][j] * SCALE_;
        sc[nf][j] = ((mw[j] >> (nf * 16 + r16)) & 1ull) ? 1e-9f : v;
      }
    // online softmax (row q = g*4+j lives on the 16 lanes of group g)
#pragma unroll
    for (int j = 0; j < 4; ++j) {
      float tm = fmaxf(fmaxf(sc[0][j], sc[1][j]), fmaxf(sc[2][j], sc[3][j]));
#pragma unroll
      for (int off = 1; off < 16; off <<= 1) tm = fmaxf(tm, __shfl_xor(tm, off));
      float mn = fmaxf(mrun[j], tm);
      corr[j] = __expf(mrun[j] - mn);
      mrun[j] = mn;
    }
#pragma unroll
    for (int nf = 0; nf < 4; ++nf)
#pragma unroll
      for (int j = 0; j < 4; ++j)
        sc[nf][j] = __expf(sc[nf][j] - mrun[j]);
#pragma unroll
    for (int j = 0; j < 4; ++j) {
      float rs = (sc[0][j] + sc[1][j]) + (sc[2][j] + sc[3][j]);
#pragma unroll
      for (int off = 1; off < 16; off <<= 1) rs += __shfl_xor(rs, off);
      lsum[j] = lsum[j] * corr[j] + rs;
    }
#pragma unroll
    for (int nf = 0; nf < 4; ++nf) {
      acc[nf].x *= corr[0]; acc[nf].y *= corr[1]; acc[nf].z *= corr[2]; acc[nf].w *= corr[3];
    }
    // P -> LDS [q][s]
#pragma unroll
    for (int nf = 0; nf < 4; ++nf)
#pragma unroll
      for (int j = 0; j < 4; ++j)
        Pq[g * 4 + j][nf * 16 + r16] = f2bf(sc[nf][j]);
    asm volatile("s_waitcnt lgkmcnt(0)" ::: "memory");

    // PV: A = P rows (contiguous), B = V^T rows
#pragma unroll
    for (int k2 = 0; k2 < 2; ++k2) {
      short8 pa = *reinterpret_cast<const short8*>(&Pq[r16][k2 * 32 + g * 8]);
#pragma unroll
      for (int nf = 0; nf < 4; ++nf) {
        short8 bv = *reinterpret_cast<const short8*>(&Vs[nf * 16 + r16][k2 * 32 + g * 8]);
        acc[nf] = __builtin_amdgcn_mfma_f32_16x16x32_bf16(pa, bv, acc[nf], 0, 0, 0);
      }
    }
    __syncthreads();
  }

  // epilogue: out[q][dk] = acc / l
#pragma unroll
  for (int nf = 0; nf < 4; ++nf)
#pragma unroll
    for (int j = 0; j < 4; ++j)
      out[(size_t)(b * S_ + q0 + g * 4 + j) * DK_ + nf * 16 + r16] = acc[nf][j] / lsum[j];
}

// ---------------------------------------------------------------------------
extern "C" void kernel_launch(void* const* d_in, const int* in_sizes, int n_in,
                              void* d_out, int out_size, void* d_ws, size_t ws_size,
                              hipStream_t stream) {
  const float* q  = (const float*)d_in[0];
  const float* k  = (const float*)d_in[1];
  const float* v  = (const float*)d_in[2];
  const void*  mk = d_in[3];
  const float* wq = (const float*)d_in[4];
  const float* wk = (const float*)d_in[5];
  const float* wv = (const float*)d_in[6];

  char* ws = (char*)d_ws;
  unsigned short* Qp   = (unsigned short*)(ws);                         // 1 MB
  unsigned short* Kp   = (unsigned short*)(ws + (1u << 20));            // 1 MB
  unsigned short* Vt   = (unsigned short*)(ws + (2u << 20));            // 1 MB  [b][dk][s]
  unsigned int*   mp   = (unsigned int*)  (ws + (3u << 20));            // 2 MB packed mask
  unsigned int*   flag = (unsigned int*)  (ws + (5u << 20));            // 4 B
  unsigned short* Wb   = (unsigned short*)(ws + (5u << 20) + 4096);     // 384 KB bf16 weights

  wconv_kernel<<<96, 256, 0, stream>>>(wq, wk, wv, Wb);
  detect_kernel<<<1, 64, 0, stream>>>((const unsigned int*)mk, flag);
  maskpack_kernel<<<2048, 256, 0, stream>>>((const unsigned char*)mk, (const unsigned int*)mk, flag, mp);
  proj2_kernel<<<dim3(512, 3), 64, 0, stream>>>(q, k, v, Wb, Qp, Kp, Vt);
  attn_kernel<<<512, 64, 0, stream>>>(Qp, Kp, Vt, mp, (float*)d_out);
}

// Round 5
// 98.614 us; speedup vs baseline: 1.2666x; 1.1688x over previous
//
#include <hip/hip_runtime.h>

// Problem constants
#define B_    4
#define S_    2048
#define DM_   1024
#define DK_   64
#define SCALE_ 0.03125f   // 1024^-0.5  (reference scales by d_model^-0.5, not d_k)

typedef float        f32x4  __attribute__((ext_vector_type(4)));
typedef float        float8 __attribute__((ext_vector_type(8)));
typedef short        short8 __attribute__((ext_vector_type(8)));
typedef float        fltx4  __attribute__((ext_vector_type(4)));
typedef unsigned int uint2v __attribute__((ext_vector_type(2)));
typedef unsigned int uint4v __attribute__((ext_vector_type(4)));

// fp32 -> bf16, round-to-nearest-even
static __device__ __forceinline__ unsigned short f2bf(float f) {
  unsigned u = __float_as_uint(f);
  u += 0x7fffu + ((u >> 16) & 1u);
  return (unsigned short)(u >> 16);
}
static __device__ __forceinline__ uint2v pack4(float a, float b, float c, float d) {
  uint2v r;
  r.x = (unsigned)f2bf(a) | ((unsigned)f2bf(b) << 16);
  r.y = (unsigned)f2bf(c) | ((unsigned)f2bf(d) << 16);
  return r;
}
static __device__ __forceinline__ short8 cvt8(float8 v) {
  short8 r;
#pragma unroll
  for (int i = 0; i < 8; ++i) r[i] = (short)f2bf(v[i]);
  return r;
}

// ---------------------------------------------------------------------------
// Kernel 0: detect mask element width (int32 of {0,1} vs byte-packed bools).
// ---------------------------------------------------------------------------
__global__ void detect_kernel(const unsigned int* __restrict__ m, unsigned int* __restrict__ flag) {
  unsigned v = m[threadIdx.x];
  unsigned long long bad = __ballot(v > 1u);
  if (threadIdx.x == 0) flag[0] = (bad != 0ull) ? 1u : 0u;
}

// ---------------------------------------------------------------------------
// Kernel W: convert the 3 weight matrices to bf16 once. Wb: [which][64][1024].
// ---------------------------------------------------------------------------
__global__ __launch_bounds__(256) void wconv_kernel(
    const float* __restrict__ wq, const float* __restrict__ wk, const float* __restrict__ wv,
    unsigned short* __restrict__ Wb)
{
  const int idx   = blockIdx.x * 256 + threadIdx.x;
  const int which = idx >> 13;
  const int e     = idx & 8191;
  const float* __restrict__ w = (which == 0) ? wq : (which == 1) ? wk : wv;
  fltx4 v0 = *reinterpret_cast<const fltx4*>(w + (size_t)e * 8);
  fltx4 v1 = *reinterpret_cast<const fltx4*>(w + (size_t)e * 8 + 4);
  uint4v o;
  o.x = (unsigned)f2bf(v0.x) | ((unsigned)f2bf(v0.y) << 16);
  o.y = (unsigned)f2bf(v0.z) | ((unsigned)f2bf(v0.w) << 16);
  o.z = (unsigned)f2bf(v1.x) | ((unsigned)f2bf(v1.y) << 16);
  o.w = (unsigned)f2bf(v1.z) | ((unsigned)f2bf(v1.w) << 16);
  *reinterpret_cast<uint4v*>(Wb + (size_t)which * 65536 + (size_t)e * 8) = o;
}

// ---------------------------------------------------------------------------
// Kernel 1: pack mask to 1 bit/element (2 MB, L2-hot). Verified R2-T3.
// ---------------------------------------------------------------------------
__global__ __launch_bounds__(256) void maskpack_kernel(const unsigned char* __restrict__ mb,
                                                       const unsigned int* __restrict__ mi,
                                                       const unsigned int* __restrict__ flag,
                                                       unsigned int* __restrict__ mp) {
  const int w = blockIdx.x * 256 + threadIdx.x;
  unsigned out = 0;
  if (flag[0]) {
    const uint4v* p = reinterpret_cast<const uint4v*>(mb + (size_t)w * 32);
    uint4v a = p[0], b = p[1];
    unsigned ws0[8];
    ws0[0]=a.x; ws0[1]=a.y; ws0[2]=a.z; ws0[3]=a.w; ws0[4]=b.x; ws0[5]=b.y; ws0[6]=b.z; ws0[7]=b.w;
#pragma unroll
    for (int i = 0; i < 8; ++i) {
      unsigned v = ws0[i];
      out |= ((v & 0x000000ffu) ? 1u : 0u) << (i * 4 + 0);
      out |= ((v & 0x0000ff00u) ? 1u : 0u) << (i * 4 + 1);
      out |= ((v & 0x00ff0000u) ? 1u : 0u) << (i * 4 + 2);
      out |= ((v & 0xff000000u) ? 1u : 0u) << (i * 4 + 3);
    }
  } else {
    const uint4v* p = reinterpret_cast<const uint4v*>(mi + (size_t)w * 32);
#pragma unroll
    for (int i = 0; i < 8; ++i) {
      uint4v a = p[i];
      out |= (a.x ? 1u : 0u) << (i * 4 + 0);
      out |= (a.y ? 1u : 0u) << (i * 4 + 1);
      out |= (a.z ? 1u : 0u) << (i * 4 + 2);
      out |= (a.w ? 1u : 0u) << (i * 4 + 3);
    }
  }
  mp[w] = out;
}

// ---------------------------------------------------------------------------
// Kernel 2 (REWRITE v3): K-split projection. 256-thread blocks, 16 x-rows.
// Wave wid owns k-range [wid*256, wid*256+256) = 8 k-steps; fully-unrolled
// inner loop (independent load addresses -> deep compiler load hoisting).
// Deterministic LDS f32 reduction across the 4 waves, then bf16 store.
//   D[m=g*4+j][n] = sum_k x[row0+m][k] * W[n][k]
// ---------------------------------------------------------------------------
__global__ __launch_bounds__(256) void proj3_kernel(
    const float* __restrict__ xq, const float* __restrict__ xk, const float* __restrict__ xv,
    const unsigned short* __restrict__ Wb,
    unsigned short* __restrict__ Qp, unsigned short* __restrict__ Kp, unsigned short* __restrict__ Vt)
{
  const int which = blockIdx.y;
  const float* __restrict__ x = (which == 0) ? xq : (which == 1) ? xk : xv;
  const int row0 = blockIdx.x * 16;
  const int tid = threadIdx.x, wid = tid >> 6, lane = tid & 63;
  const int g = lane >> 4, r16 = lane & 15;

  const float* __restrict__ xrow = x + (size_t)(row0 + r16) * DM_ + wid * 256 + g * 8;
  const unsigned short* __restrict__ wbase = Wb + (size_t)which * 65536 + wid * 256 + g * 8;

  f32x4 acc[4];
#pragma unroll
  for (int i = 0; i < 4; ++i) { acc[i].x = 0.f; acc[i].y = 0.f; acc[i].z = 0.f; acc[i].w = 0.f; }

#pragma unroll
  for (int kc = 0; kc < 8; ++kc) {
    float8 xa = *reinterpret_cast<const float8*>(xrow + kc * 32);
    short8 w0 = *reinterpret_cast<const short8*>(wbase + (size_t)(0 * 16 + r16) * DM_ + kc * 32);
    short8 w1 = *reinterpret_cast<const short8*>(wbase + (size_t)(1 * 16 + r16) * DM_ + kc * 32);
    short8 w2 = *reinterpret_cast<const short8*>(wbase + (size_t)(2 * 16 + r16) * DM_ + kc * 32);
    short8 w3 = *reinterpret_cast<const short8*>(wbase + (size_t)(3 * 16 + r16) * DM_ + kc * 32);
    short8 a = cvt8(xa);
    acc[0] = __builtin_amdgcn_mfma_f32_16x16x32_bf16(a, w0, acc[0], 0, 0, 0);
    acc[1] = __builtin_amdgcn_mfma_f32_16x16x32_bf16(a, w1, acc[1], 0, 0, 0);
    acc[2] = __builtin_amdgcn_mfma_f32_16x16x32_bf16(a, w2, acc[2], 0, 0, 0);
    acc[3] = __builtin_amdgcn_mfma_f32_16x16x32_bf16(a, w3, acc[3], 0, 0, 0);
  }

  __shared__ f32x4 red[4][4][64];   // [wid][nf][lane], 16 KB
#pragma unroll
  for (int nf = 0; nf < 4; ++nf) red[wid][nf][lane] = acc[nf];
  __syncthreads();

  // thread (wid, lane) reduces + stores fragment nf = wid
  f32x4 s = red[0][wid][lane];
#pragma unroll
  for (int w = 1; w < 4; ++w) {
    f32x4 t = red[w][wid][lane];
    s.x += t.x; s.y += t.y; s.z += t.z; s.w += t.w;
  }

  if (which < 2) {
    unsigned short* __restrict__ dst = (which == 0) ? Qp : Kp;
#pragma unroll
    for (int j = 0; j < 4; ++j)
      dst[(size_t)(row0 + g * 4 + j) * DK_ + wid * 16 + r16] = f2bf(s[j]);
  } else {
    const int grow = row0 + g * 4;
    const int bb = grow >> 11, sin = grow & 2047;
    *reinterpret_cast<uint2v*>(Vt + (size_t)(bb * DK_ + wid * 16 + r16) * S_ + sin) =
        pack4(s.x, s.y, s.z, s.w);
  }
}

// ---------------------------------------------------------------------------
// Kernel 3a: flash attention PARTIAL (split-S x4). blockIdx.x = sp*512 + qw;
// wave scans s-tiles [sp*8, sp*8+8) and writes unnormalized acc + (m, l).
// Body identical to the verified R3/R4 attn tile pipeline.
// ---------------------------------------------------------------------------
__global__ __launch_bounds__(64) void attn_part_kernel(
    const unsigned short* __restrict__ Qp, const unsigned short* __restrict__ Kp,
    const unsigned short* __restrict__ Vt, const unsigned int* __restrict__ mp,
    float* __restrict__ pacc, float* __restrict__ pm, float* __restrict__ pl)
{
  const int lane = threadIdx.x;
  const int g = lane >> 4, r16 = lane & 15;
  const int bx = blockIdx.x;
  const int sp = bx >> 9;            // split 0..3
  const int qw = bx & 511;           // global q-tile
  const int b  = qw >> 7;
  const int q0 = (qw & 127) * 16;

  __shared__ __align__(16) unsigned short Kt[64][72];
  __shared__ __align__(16) unsigned short Vs[64][72];
  __shared__ __align__(16) unsigned short Pq[16][72];

  short8 aq0, aq1;
  {
    const unsigned short* qrow = Qp + (size_t)(b * S_ + q0 + r16) * DK_ + g * 8;
    aq0 = *reinterpret_cast<const short8*>(qrow);
    aq1 = *reinterpret_cast<const short8*>(qrow + 32);
  }

  float mrun[4], lsum[4], corr[4];
  f32x4 acc[4];
#pragma unroll
  for (int j = 0; j < 4; ++j) { mrun[j] = -3.0e38f; lsum[j] = 0.f; }
#pragma unroll
  for (int nf = 0; nf < 4; ++nf) { acc[nf].x = 0.f; acc[nf].y = 0.f; acc[nf].z = 0.f; acc[nf].w = 0.f; }

  const int srow_stage = lane >> 3, sgran = lane & 7;

  for (int st = sp * 8; st < sp * 8 + 8; ++st) {
    const int s0 = st * 64;
#pragma unroll
    for (int i = 0; i < 8; ++i) {
      int r = i * 8 + srow_stage;
      uint4v kv = *reinterpret_cast<const uint4v*>(Kp + (size_t)(b * S_ + s0 + r) * DK_ + sgran * 8);
      *reinterpret_cast<uint4v*>(&Kt[r][sgran * 8]) = kv;
      uint4v vv = *reinterpret_cast<const uint4v*>(Vt + (size_t)(b * DK_ + r) * S_ + s0 + sgran * 8);
      *reinterpret_cast<uint4v*>(&Vs[r][sgran * 8]) = vv;
    }
    unsigned long long mw[4];
#pragma unroll
    for (int j = 0; j < 4; ++j) {
      size_t widx = ((size_t)(b * S_ + q0 + g * 4 + j) * S_ + s0) >> 5;
      mw[j] = *reinterpret_cast<const unsigned long long*>(mp + widx);
    }
    __syncthreads();

    f32x4 sc[4];
#pragma unroll
    for (int nf = 0; nf < 4; ++nf) { sc[nf].x = 0.f; sc[nf].y = 0.f; sc[nf].z = 0.f; sc[nf].w = 0.f; }
#pragma unroll
    for (int nf = 0; nf < 4; ++nf) {
      short8 bk0 = *reinterpret_cast<const short8*>(&Kt[nf * 16 + r16][g * 8]);
      short8 bk1 = *reinterpret_cast<const short8*>(&Kt[nf * 16 + r16][32 + g * 8]);
      sc[nf] = __builtin_amdgcn_mfma_f32_16x16x32_bf16(aq0, bk0, sc[nf], 0, 0, 0);
      sc[nf] = __builtin_amdgcn_mfma_f32_16x16x32_bf16(aq1, bk1, sc[nf], 0, 0, 0);
    }
#pragma unroll
    for (int nf = 0; nf < 4; ++nf)
#pragma unroll
      for (int j = 0; j < 4; ++j) {
        float v = sc[nf][j] * SCALE_;
        sc[nf][j] = ((mw[j] >> (nf * 16 + r16)) & 1ull) ? 1e-9f : v;
      }
#pragma unroll
    for (int j = 0; j < 4; ++j) {
      float tm = fmaxf(fmaxf(sc[0][j], sc[1][j]), fmaxf(sc[2][j], sc[3][j]));
#pragma unroll
      for (int off = 1; off < 16; off <<= 1) tm = fmaxf(tm, __shfl_xor(tm, off));
      float mn = fmaxf(mrun[j], tm);
      corr[j] = __expf(mrun[j] - mn);
      mrun[j] = mn;
    }
#pragma unroll
    for (int nf = 0; nf < 4; ++nf)
#pragma unroll
      for (int j = 0; j < 4; ++j)
        sc[nf][j] = __expf(sc[nf][j] - mrun[j]);
#pragma unroll
    for (int j = 0; j < 4; ++j) {
      float rs = (sc[0][j] + sc[1][j]) + (sc[2][j] + sc[3][j]);
#pragma unroll
      for (int off = 1; off < 16; off <<= 1) rs += __shfl_xor(rs, off);
      lsum[j] = lsum[j] * corr[j] + rs;
    }
#pragma unroll
    for (int nf = 0; nf < 4; ++nf) {
      acc[nf].x *= corr[0]; acc[nf].y *= corr[1]; acc[nf].z *= corr[2]; acc[nf].w *= corr[3];
    }
#pragma unroll
    for (int nf = 0; nf < 4; ++nf)
#pragma unroll
      for (int j = 0; j < 4; ++j)
        Pq[g * 4 + j][nf * 16 + r16] = f2bf(sc[nf][j]);
    asm volatile("s_waitcnt lgkmcnt(0)" ::: "memory");

#pragma unroll
    for (int k2 = 0; k2 < 2; ++k2) {
      short8 pa = *reinterpret_cast<const short8*>(&Pq[r16][k2 * 32 + g * 8]);
#pragma unroll
      for (int nf = 0; nf < 4; ++nf) {
        short8 bv = *reinterpret_cast<const short8*>(&Vs[nf * 16 + r16][k2 * 32 + g * 8]);
        acc[nf] = __builtin_amdgcn_mfma_f32_16x16x32_bf16(pa, bv, acc[nf], 0, 0, 0);
      }
    }
    __syncthreads();
  }

  // write partials (NO normalization)
  float* __restrict__ pa = pacc + (size_t)(sp * 512 + qw) * 1024;
#pragma unroll
  for (int nf = 0; nf < 4; ++nf)
#pragma unroll
    for (int j = 0; j < 4; ++j)
      pa[(g * 4 + j) * 64 + nf * 16 + r16] = acc[nf][j];
  if (r16 == 0) {
#pragma unroll
    for (int j = 0; j < 4; ++j) {
      pm[(sp * 512 + qw) * 16 + g * 4 + j] = mrun[j];
      pl[(sp * 512 + qw) * 16 + g * 4 + j] = lsum[j];
    }
  }
}

// ---------------------------------------------------------------------------
// Kernel 3b: merge 4 split partials. 512 blocks x 64 lanes (lane = dk col).
// out[row][col] = sum_i w_i acc_i[row][col] / sum_i w_i l_i, w_i=exp(m_i-M).
// ---------------------------------------------------------------------------
__global__ __launch_bounds__(64) void attn_merge_kernel(
    const float* __restrict__ pacc, const float* __restrict__ pm, const float* __restrict__ pl,
    float* __restrict__ out)
{
  const int qw = blockIdx.x;
  const int b = qw >> 7, q0 = (qw & 127) * 16;
  const int lane = threadIdx.x;

#pragma unroll 1
  for (int row = 0; row < 16; ++row) {
    float m0 = pm[(0 * 512 + qw) * 16 + row], m1 = pm[(1 * 512 + qw) * 16 + row];
    float m2 = pm[(2 * 512 + qw) * 16 + row], m3 = pm[(3 * 512 + qw) * 16 + row];
    float M = fmaxf(fmaxf(m0, m1), fmaxf(m2, m3));
    float w0 = __expf(m0 - M), w1 = __expf(m1 - M), w2 = __expf(m2 - M), w3 = __expf(m3 - M);
    float L = w0 * pl[(0 * 512 + qw) * 16 + row] + w1 * pl[(1 * 512 + qw) * 16 + row] +
              w2 * pl[(2 * 512 + qw) * 16 + row] + w3 * pl[(3 * 512 + qw) * 16 + row];
    float v = w0 * pacc[((size_t)(0 * 512 + qw) * 16 + row) * 64 + lane] +
              w1 * pacc[((size_t)(1 * 512 + qw) * 16 + row) * 64 + lane] +
              w2 * pacc[((size_t)(2 * 512 + qw) * 16 + row) * 64 + lane] +
              w3 * pacc[((size_t)(3 * 512 + qw) * 16 + row) * 64 + lane];
    out[(size_t)(b * S_ + q0 + row) * DK_ + lane] = v / L;
  }
}

// ---------------------------------------------------------------------------
// Kernel 3 (fallback, used only if ws too small for split buffers):
// R3/R4 verified single-pass attention.
// ---------------------------------------------------------------------------
__global__ __launch_bounds__(64) void attn_kernel(
    const unsigned short* __restrict__ Qp, const unsigned short* __restrict__ Kp,
    const unsigned short* __restrict__ Vt, const unsigned int* __restrict__ mp,
    float* __restrict__ out)
{
  const int lane = threadIdx.x;
  const int g = lane >> 4, r16 = lane & 15;
  const int qt = blockIdx.x & 127;
  const int b  = blockIdx.x >> 7;
  const int q0 = qt * 16;

  __shared__ __align__(16) unsigned short Kt[64][72];
  __shared__ __align__(16) unsigned short Vs[64][72];
  __shared__ __align__(16) unsigned short Pq[16][72];

  short8 aq0, aq1;
  {
    const unsigned short* qrow = Qp + (size_t)(b * S_ + q0 + r16) * DK_ + g * 8;
    aq0 = *reinterpret_cast<const short8*>(qrow);
    aq1 = *reinterpret_cast<const short8*>(qrow + 32);
  }

  float mrun[4], lsum[4], corr[4];
  f32x4 acc[4];
#pragma unroll
  for (int j = 0; j < 4; ++j) { mrun[j] = -3.0e38f; lsum[j] = 0.f; }
#pragma unroll
  for (int nf = 0; nf < 4; ++nf) { acc[nf].x = 0.f; acc[nf].y = 0.f; acc[nf].z = 0.f; acc[nf].w = 0.f; }

  const int srow_stage = lane >> 3, sgran = lane & 7;

  for (int st = 0; st < 32; ++st) {
    const int s0 = st * 64;
#pragma unroll
    for (int i = 0; i < 8; ++i) {
      int r = i * 8 + srow_stage;
      uint4v kv = *reinterpret_cast<const uint4v*>(Kp + (size_t)(b * S_ + s0 + r) * DK_ + sgran * 8);
      *reinterpret_cast<uint4v*>(&Kt[r][sgran * 8]) = kv;
      uint4v vv = *reinterpret_cast<const uint4v*>(Vt + (size_t)(b * DK_ + r) * S_ + s0 + sgran * 8);
      *reinterpret_cast<uint4v*>(&Vs[r][sgran * 8]) = vv;
    }
    unsigned long long mw[4];
#pragma unroll
    for (int j = 0; j < 4; ++j) {
      size_t widx = ((size_t)(b * S_ + q0 + g * 4 + j) * S_ + s0) >> 5;
      mw[j] = *reinterpret_cast<const unsigned long long*>(mp + widx);
    }
    __syncthreads();

    f32x4 sc[4];
#pragma unroll
    for (int nf = 0; nf < 4; ++nf) { sc[nf].x = 0.f; sc[nf].y = 0.f; sc[nf].z = 0.f; sc[nf].w = 0.f; }
#pragma unroll
    for (int nf = 0; nf < 4; ++nf) {
      short8 bk0 = *reinterpret_cast<const short8*>(&Kt[nf * 16 + r16][g * 8]);
      short8 bk1 = *reinterpret_cast<const short8*>(&Kt[nf * 16 + r16][32 + g * 8]);
      sc[nf] = __builtin_amdgcn_mfma_f32_16x16x32_bf16(aq0, bk0, sc[nf], 0, 0, 0);
      sc[nf] = __builtin_amdgcn_mfma_f32_16x16x32_bf16(aq1, bk1, sc[nf], 0, 0, 0);
    }
#pragma unroll
    for (int nf = 0; nf < 4; ++nf)
#pragma unroll
      for (int j = 0; j < 4; ++j) {
        float v = sc[nf][j] * SCALE_;
        sc[nf][j] = ((mw[j] >> (nf * 16 + r16)) & 1ull) ? 1e-9f : v;
      }
#pragma unroll
    for (int j = 0; j < 4; ++j) {
      float tm = fmaxf(fmaxf(sc[0][j], sc[1][j]), fmaxf(sc[2][j], sc[3][j]));
#pragma unroll
      for (int off = 1; off < 16; off <<= 1) tm = fmaxf(tm, __shfl_xor(tm, off));
      float mn = fmaxf(mrun[j], tm);
      corr[j] = __expf(mrun[j] - mn);
      mrun[j] = mn;
    }
#pragma unroll
    for (int nf = 0; nf < 4; ++nf)
#pragma unroll
      for (int j = 0; j < 4; ++j)
        sc[nf][j] = __expf(sc[nf][j] - mrun[j]);
#pragma unroll
    for (int j = 0; j < 4; ++j) {
      float rs = (sc[0][j] + sc[1][j]) + (sc[2][j] + sc[3][j]);
#pragma unroll
      for (int off = 1; off < 16; off <<= 1) rs += __shfl_xor(rs, off);
      lsum[j] = lsum[j] * corr[j] + rs;
    }
#pragma unroll
    for (int nf = 0; nf < 4; ++nf) {
      acc[nf].x *= corr[0]; acc[nf].y *= corr[1]; acc[nf].z *= corr[2]; acc[nf].w *= corr[3];
    }
#pragma unroll
    for (int nf = 0; nf < 4; ++nf)
#pragma unroll
      for (int j = 0; j < 4; ++j)
        Pq[g * 4 + j][nf * 16 + r16] = f2bf(sc[nf][j]);
    asm volatile("s_waitcnt lgkmcnt(0)" ::: "memory");

#pragma unroll
    for (int k2 = 0; k2 < 2; ++k2) {
      short8 pa = *reinterpret_cast<const short8*>(&Pq[r16][k2 * 32 + g * 8]);
#pragma unroll
      for (int nf = 0; nf < 4; ++nf) {
        short8 bv = *reinterpret_cast<const short8*>(&Vs[nf * 16 + r16][k2 * 32 + g * 8]);
        acc[nf] = __builtin_amdgcn_mfma_f32_16x16x32_bf16(pa, bv, acc[nf], 0, 0, 0);
      }
    }
    __syncthreads();
  }

#pragma unroll
  for (int nf = 0; nf < 4; ++nf)
#pragma unroll
    for (int j = 0; j < 4; ++j)
      out[(size_t)(b * S_ + q0 + g * 4 + j) * DK_ + nf * 16 + r16] = acc[nf][j] / lsum[j];
}

// ---------------------------------------------------------------------------
extern "C" void kernel_launch(void* const* d_in, const int* in_sizes, int n_in,
                              void* d_out, int out_size, void* d_ws, size_t ws_size,
                              hipStream_t stream) {
  const float* q  = (const float*)d_in[0];
  const float* k  = (const float*)d_in[1];
  const float* v  = (const float*)d_in[2];
  const void*  mk = d_in[3];
  const float* wq = (const float*)d_in[4];
  const float* wk = (const float*)d_in[5];
  const float* wv = (const float*)d_in[6];

  char* ws = (char*)d_ws;
  unsigned short* Qp   = (unsigned short*)(ws);                         // 1 MB
  unsigned short* Kp   = (unsigned short*)(ws + (1u << 20));            // 1 MB
  unsigned short* Vt   = (unsigned short*)(ws + (2u << 20));            // 1 MB  [b][dk][s]
  unsigned int*   mp   = (unsigned int*)  (ws + (3u << 20));            // 2 MB packed mask
  unsigned int*   flag = (unsigned int*)  (ws + (5u << 20));            // 4 B
  unsigned short* Wb   = (unsigned short*)(ws + (5u << 20) + 4096);     // 384 KB bf16 weights
  float*          pacc = (float*)(ws + (6u << 20));                     // 8 MB partial acc
  float*          pm   = (float*)(ws + (14u << 20));                    // 128 KB partial m
  float*          pl   = (float*)(ws + (14u << 20) + (1u << 17));       // 128 KB partial l

  wconv_kernel<<<96, 256, 0, stream>>>(wq, wk, wv, Wb);
  detect_kernel<<<1, 64, 0, stream>>>((const unsigned int*)mk, flag);
  maskpack_kernel<<<2048, 256, 0, stream>>>((const unsigned char*)mk, (const unsigned int*)mk, flag, mp);
  proj3_kernel<<<dim3(512, 3), 256, 0, stream>>>(q, k, v, Wb, Qp, Kp, Vt);

  if (ws_size >= (15u << 20)) {
    attn_part_kernel<<<2048, 64, 0, stream>>>(Qp, Kp, Vt, mp, pacc, pm, pl);
    attn_merge_kernel<<<512, 64, 0, stream>>>(pacc, pm, pl, (float*)d_out);
  } else {
    attn_kernel<<<512, 64, 0, stream>>>(Qp, Kp, Vt, mp, (float*)d_out);
  }
}

// Round 6
// 86.963 us; speedup vs baseline: 1.4363x; 1.1340x over previous
//
#include <hip/hip_runtime.h>

// Problem constants
#define B_    4
#define S_    2048
#define DM_   1024
#define DK_   64
#define SCALE_ 0.03125f   // 1024^-0.5  (reference scales by d_model^-0.5, not d_k)

typedef float        f32x4  __attribute__((ext_vector_type(4)));
typedef float        float8 __attribute__((ext_vector_type(8)));
typedef short        short8 __attribute__((ext_vector_type(8)));
typedef float        fltx4  __attribute__((ext_vector_type(4)));
typedef unsigned int uint2v __attribute__((ext_vector_type(2)));
typedef unsigned int uint4v __attribute__((ext_vector_type(4)));

// async global->LDS DMA, 16 B per lane. LDS dest is WAVE-UNIFORM base
// (hardware adds lane*16); global src is per-lane.
#define GLL16(gsrc, ldst)                                                   \
  __builtin_amdgcn_global_load_lds(                                         \
      (const __attribute__((address_space(1))) void*)(gsrc),                \
      (__attribute__((address_space(3))) void*)(ldst), 16, 0, 0)

// fp32 -> bf16, round-to-nearest-even
static __device__ __forceinline__ unsigned short f2bf(float f) {
  unsigned u = __float_as_uint(f);
  u += 0x7fffu + ((u >> 16) & 1u);
  return (unsigned short)(u >> 16);
}
static __device__ __forceinline__ uint2v pack4(float a, float b, float c, float d) {
  uint2v r;
  r.x = (unsigned)f2bf(a) | ((unsigned)f2bf(b) << 16);
  r.y = (unsigned)f2bf(c) | ((unsigned)f2bf(d) << 16);
  return r;
}

// ---------------------------------------------------------------------------
// Kernel 0: detect mask element width (int32 of {0,1} vs byte-packed bools).
// ---------------------------------------------------------------------------
__global__ void detect_kernel(const unsigned int* __restrict__ m, unsigned int* __restrict__ flag) {
  unsigned v = m[threadIdx.x];
  unsigned long long bad = __ballot(v > 1u);
  if (threadIdx.x == 0) flag[0] = (bad != 0ull) ? 1u : 0u;
}

// ---------------------------------------------------------------------------
// Kernel W: convert the 3 weight matrices to bf16 once. Wb: [which][64][1024].
// ---------------------------------------------------------------------------
__global__ __launch_bounds__(256) void wconv_kernel(
    const float* __restrict__ wq, const float* __restrict__ wk, const float* __restrict__ wv,
    unsigned short* __restrict__ Wb)
{
  const int idx   = blockIdx.x * 256 + threadIdx.x;
  const int which = idx >> 13;
  const int e     = idx & 8191;
  const float* __restrict__ w = (which == 0) ? wq : (which == 1) ? wk : wv;
  fltx4 v0 = *reinterpret_cast<const fltx4*>(w + (size_t)e * 8);
  fltx4 v1 = *reinterpret_cast<const fltx4*>(w + (size_t)e * 8 + 4);
  uint4v o;
  o.x = (unsigned)f2bf(v0.x) | ((unsigned)f2bf(v0.y) << 16);
  o.y = (unsigned)f2bf(v0.z) | ((unsigned)f2bf(v0.w) << 16);
  o.z = (unsigned)f2bf(v1.x) | ((unsigned)f2bf(v1.y) << 16);
  o.w = (unsigned)f2bf(v1.z) | ((unsigned)f2bf(v1.w) << 16);
  *reinterpret_cast<uint4v*>(Wb + (size_t)which * 65536 + (size_t)e * 8) = o;
}

// ---------------------------------------------------------------------------
// Kernel 1: pack mask to 1 bit/element (2 MB, L2-hot). Verified R2-T3.
// ---------------------------------------------------------------------------
__global__ __launch_bounds__(256) void maskpack_kernel(const unsigned char* __restrict__ mb,
                                                       const unsigned int* __restrict__ mi,
                                                       const unsigned int* __restrict__ flag,
                                                       unsigned int* __restrict__ mp) {
  const int w = blockIdx.x * 256 + threadIdx.x;
  unsigned out = 0;
  if (flag[0]) {
    const uint4v* p = reinterpret_cast<const uint4v*>(mb + (size_t)w * 32);
    uint4v a = p[0], b = p[1];
    unsigned ws0[8];
    ws0[0]=a.x; ws0[1]=a.y; ws0[2]=a.z; ws0[3]=a.w; ws0[4]=b.x; ws0[5]=b.y; ws0[6]=b.z; ws0[7]=b.w;
#pragma unroll
    for (int i = 0; i < 8; ++i) {
      unsigned v = ws0[i];
      out |= ((v & 0x000000ffu) ? 1u : 0u) << (i * 4 + 0);
      out |= ((v & 0x0000ff00u) ? 1u : 0u) << (i * 4 + 1);
      out |= ((v & 0x00ff0000u) ? 1u : 0u) << (i * 4 + 2);
      out |= ((v & 0xff000000u) ? 1u : 0u) << (i * 4 + 3);
    }
  } else {
    const uint4v* p = reinterpret_cast<const uint4v*>(mi + (size_t)w * 32);
#pragma unroll
    for (int i = 0; i < 8; ++i) {
      uint4v a = p[i];
      out |= (a.x ? 1u : 0u) << (i * 4 + 0);
      out |= (a.y ? 1u : 0u) << (i * 4 + 1);
      out |= (a.z ? 1u : 0u) << (i * 4 + 2);
      out |= (a.w ? 1u : 0u) << (i * 4 + 3);
    }
  }
  mp[w] = out;
}

// ---------------------------------------------------------------------------
// Kernel 2 (REWRITE v4): m97-style staged projection via global_load_lds.
// grid (128, 3), 256 threads. Tile = 64 rows x K-step 128, 8 K-steps.
// LDS: Xs f32 [64][128] (32 KB) + Ws bf16 [64][128] (16 KB), single-buffered.
// Staging DMA keeps 48 KB in flight per block with zero VGPR cost.
// LDS linear for DMA dest; 16-B-granule XOR swizzle (granule ^= row&15)
// applied to the GLOBAL SOURCE at stage time and to reads (rule: both sides).
// Wave wid owns rows [wid*16, wid*16+16); D[m=g*4+j][n=nf*16+r16] (T1 layout).
// ---------------------------------------------------------------------------
__global__ __launch_bounds__(256) void proj4_kernel(
    const float* __restrict__ xq, const float* __restrict__ xk, const float* __restrict__ xv,
    const unsigned short* __restrict__ Wb,
    unsigned short* __restrict__ Qp, unsigned short* __restrict__ Kp, unsigned short* __restrict__ Vt)
{
  const int which = blockIdx.y;
  const float* __restrict__ x = (which == 0) ? xq : (which == 1) ? xk : xv;
  const unsigned short* __restrict__ wsrc = Wb + (size_t)which * 65536;
  const int row0 = blockIdx.x * 64;
  const int tid = threadIdx.x, wid = tid >> 6;
  const int lane = tid & 63, g = lane >> 4, r16 = lane & 15;

  __shared__ __align__(16) float          XsF[8192];   // 64x128 f32 (swizzled content)
  __shared__ __align__(16) unsigned short WsH[8192];   // 64x128 bf16 (swizzled content)

  f32x4 acc[4];
#pragma unroll
  for (int i = 0; i < 4; ++i) { acc[i].x = 0.f; acc[i].y = 0.f; acc[i].z = 0.f; acc[i].w = 0.f; }

  // precompute per-thread inverse-swizzled source coordinates (kb-independent)
  int xrow[8], xcol[8];
#pragma unroll
  for (int i = 0; i < 8; ++i) {
    int L = i * 4096 + tid * 16;              // linear LDS byte this thread's DMA writes
    int U = L ^ (((L >> 9) & 15) << 4);       // unswizzled logical byte
    xrow[i] = U >> 9;                         // row (pitch 512 B)
    xcol[i] = (U & 511) >> 2;                 // float col
  }
  int wrow[4], wcol[4];
#pragma unroll
  for (int i = 0; i < 4; ++i) {
    int L = i * 4096 + tid * 16;
    int U = L ^ (((L >> 8) & 15) << 4);
    wrow[i] = U >> 8;                         // n (pitch 256 B)
    wcol[i] = (U & 255) >> 1;                 // bf16 col
  }

  for (int kb = 0; kb < 8; ++kb) {
    const int k0 = kb * 128;
    // stage X: 8 x 4 KB DMA
#pragma unroll
    for (int i = 0; i < 8; ++i)
      GLL16(x + (size_t)(row0 + xrow[i]) * DM_ + k0 + xcol[i],
            (char*)XsF + i * 4096 + wid * 1024);
    // stage W: 4 x 4 KB DMA
#pragma unroll
    for (int i = 0; i < 4; ++i)
      GLL16(wsrc + (size_t)wrow[i] * DM_ + k0 + wcol[i],
            (char*)WsH + i * 4096 + wid * 1024);
    __syncthreads();   // drains vmcnt -> staged data visible

#pragma unroll
    for (int k2 = 0; k2 < 4; ++k2) {
      // A-frag: row = wid*16 + r16, k = k2*32 + g*8 .. +8  (f32 -> bf16)
      const int la  = (wid * 16 + r16) * 512 + k2 * 128 + g * 32;
      const int pa0 = la ^ (r16 << 4);
      const int pa1 = (la + 16) ^ (r16 << 4);
      fltx4 a0 = *reinterpret_cast<const fltx4*>((const char*)XsF + pa0);
      fltx4 a1 = *reinterpret_cast<const fltx4*>((const char*)XsF + pa1);
      short8 a;
      a[0] = (short)f2bf(a0.x); a[1] = (short)f2bf(a0.y);
      a[2] = (short)f2bf(a0.z); a[3] = (short)f2bf(a0.w);
      a[4] = (short)f2bf(a1.x); a[5] = (short)f2bf(a1.y);
      a[6] = (short)f2bf(a1.z); a[7] = (short)f2bf(a1.w);
#pragma unroll
      for (int nf = 0; nf < 4; ++nf) {
        const int lb = (nf * 16 + r16) * 256 + k2 * 64 + g * 16;
        const int pb = lb ^ (r16 << 4);
        short8 b = *reinterpret_cast<const short8*>((const char*)WsH + pb);
        acc[nf] = __builtin_amdgcn_mfma_f32_16x16x32_bf16(a, b, acc[nf], 0, 0, 0);
      }
    }
    __syncthreads();   // before next stage overwrites
  }

  // store: row = row0 + wid*16 + g*4 + j, n = nf*16 + r16
  if (which < 2) {
    unsigned short* __restrict__ dst = (which == 0) ? Qp : Kp;
#pragma unroll
    for (int nf = 0; nf < 4; ++nf)
#pragma unroll
      for (int j = 0; j < 4; ++j)
        dst[(size_t)(row0 + wid * 16 + g * 4 + j) * DK_ + nf * 16 + r16] = f2bf(acc[nf][j]);
  } else {
    const int grow = row0 + wid * 16 + g * 4;
    const int bb = grow >> 11, sin = grow & 2047;
#pragma unroll
    for (int nf = 0; nf < 4; ++nf)
      *reinterpret_cast<uint2v*>(Vt + (size_t)(bb * DK_ + nf * 16 + r16) * S_ + sin) =
          pack4(acc[nf][0], acc[nf][1], acc[nf][2], acc[nf][3]);
  }
}

// ---------------------------------------------------------------------------
// Kernel 3a: flash attention PARTIAL (split-S x4). UNCHANGED from R5 (passed).
// ---------------------------------------------------------------------------
__global__ __launch_bounds__(64) void attn_part_kernel(
    const unsigned short* __restrict__ Qp, const unsigned short* __restrict__ Kp,
    const unsigned short* __restrict__ Vt, const unsigned int* __restrict__ mp,
    float* __restrict__ pacc, float* __restrict__ pm, float* __restrict__ pl)
{
  const int lane = threadIdx.x;
  const int g = lane >> 4, r16 = lane & 15;
  const int bx = blockIdx.x;
  const int sp = bx >> 9;
  const int qw = bx & 511;
  const int b  = qw >> 7;
  const int q0 = (qw & 127) * 16;

  __shared__ __align__(16) unsigned short Kt[64][72];
  __shared__ __align__(16) unsigned short Vs[64][72];
  __shared__ __align__(16) unsigned short Pq[16][72];

  short8 aq0, aq1;
  {
    const unsigned short* qrow = Qp + (size_t)(b * S_ + q0 + r16) * DK_ + g * 8;
    aq0 = *reinterpret_cast<const short8*>(qrow);
    aq1 = *reinterpret_cast<const short8*>(qrow + 32);
  }

  float mrun[4], lsum[4], corr[4];
  f32x4 acc[4];
#pragma unroll
  for (int j = 0; j < 4; ++j) { mrun[j] = -3.0e38f; lsum[j] = 0.f; }
#pragma unroll
  for (int nf = 0; nf < 4; ++nf) { acc[nf].x = 0.f; acc[nf].y = 0.f; acc[nf].z = 0.f; acc[nf].w = 0.f; }

  const int srow_stage = lane >> 3, sgran = lane & 7;

  for (int st = sp * 8; st < sp * 8 + 8; ++st) {
    const int s0 = st * 64;
#pragma unroll
    for (int i = 0; i < 8; ++i) {
      int r = i * 8 + srow_stage;
      uint4v kv = *reinterpret_cast<const uint4v*>(Kp + (size_t)(b * S_ + s0 + r) * DK_ + sgran * 8);
      *reinterpret_cast<uint4v*>(&Kt[r][sgran * 8]) = kv;
      uint4v vv = *reinterpret_cast<const uint4v*>(Vt + (size_t)(b * DK_ + r) * S_ + s0 + sgran * 8);
      *reinterpret_cast<uint4v*>(&Vs[r][sgran * 8]) = vv;
    }
    unsigned long long mw[4];
#pragma unroll
    for (int j = 0; j < 4; ++j) {
      size_t widx = ((size_t)(b * S_ + q0 + g * 4 + j) * S_ + s0) >> 5;
      mw[j] = *reinterpret_cast<const unsigned long long*>(mp + widx);
    }
    __syncthreads();

    f32x4 sc[4];
#pragma unroll
    for (int nf = 0; nf < 4; ++nf) { sc[nf].x = 0.f; sc[nf].y = 0.f; sc[nf].z = 0.f; sc[nf].w = 0.f; }
#pragma unroll
    for (int nf = 0; nf < 4; ++nf) {
      short8 bk0 = *reinterpret_cast<const short8*>(&Kt[nf * 16 + r16][g * 8]);
      short8 bk1 = *reinterpret_cast<const short8*>(&Kt[nf * 16 + r16][32 + g * 8]);
      sc[nf] = __builtin_amdgcn_mfma_f32_16x16x32_bf16(aq0, bk0, sc[nf], 0, 0, 0);
      sc[nf] = __builtin_amdgcn_mfma_f32_16x16x32_bf16(aq1, bk1, sc[nf], 0, 0, 0);
    }
#pragma unroll
    for (int nf = 0; nf < 4; ++nf)
#pragma unroll
      for (int j = 0; j < 4; ++j) {
        float v = sc[nf][j] * SCALE_;
        sc[nf][j] = ((mw[j] >> (nf * 16 + r16)) & 1ull) ? 1e-9f : v;
      }
#pragma unroll
    for (int j = 0; j < 4; ++j) {
      float tm = fmaxf(fmaxf(sc[0][j], sc[1][j]), fmaxf(sc[2][j], sc[3][j]));
#pragma unroll
      for (int off = 1; off < 16; off <<= 1) tm = fmaxf(tm, __shfl_xor(tm, off));
      float mn = fmaxf(mrun[j], tm);
      corr[j] = __expf(mrun[j] - mn);
      mrun[j] = mn;
    }
#pragma unroll
    for (int nf = 0; nf < 4; ++nf)
#pragma unroll
      for (int j = 0; j < 4; ++j)
        sc[nf][j] = __expf(sc[nf][j] - mrun[j]);
#pragma unroll
    for (int j = 0; j < 4; ++j) {
      float rs = (sc[0][j] + sc[1][j]) + (sc[2][j] + sc[3][j]);
#pragma unroll
      for (int off = 1; off < 16; off <<= 1) rs += __shfl_xor(rs, off);
      lsum[j] = lsum[j] * corr[j] + rs;
    }
#pragma unroll
    for (int nf = 0; nf < 4; ++nf) {
      acc[nf].x *= corr[0]; acc[nf].y *= corr[1]; acc[nf].z *= corr[2]; acc[nf].w *= corr[3];
    }
#pragma unroll
    for (int nf = 0; nf < 4; ++nf)
#pragma unroll
      for (int j = 0; j < 4; ++j)
        Pq[g * 4 + j][nf * 16 + r16] = f2bf(sc[nf][j]);
    asm volatile("s_waitcnt lgkmcnt(0)" ::: "memory");

#pragma unroll
    for (int k2 = 0; k2 < 2; ++k2) {
      short8 pa = *reinterpret_cast<const short8*>(&Pq[r16][k2 * 32 + g * 8]);
#pragma unroll
      for (int nf = 0; nf < 4; ++nf) {
        short8 bv = *reinterpret_cast<const short8*>(&Vs[nf * 16 + r16][k2 * 32 + g * 8]);
        acc[nf] = __builtin_amdgcn_mfma_f32_16x16x32_bf16(pa, bv, acc[nf], 0, 0, 0);
      }
    }
    __syncthreads();
  }

  float* __restrict__ pa = pacc + (size_t)(sp * 512 + qw) * 1024;
#pragma unroll
  for (int nf = 0; nf < 4; ++nf)
#pragma unroll
    for (int j = 0; j < 4; ++j)
      pa[(g * 4 + j) * 64 + nf * 16 + r16] = acc[nf][j];
  if (r16 == 0) {
#pragma unroll
    for (int j = 0; j < 4; ++j) {
      pm[(sp * 512 + qw) * 16 + g * 4 + j] = mrun[j];
      pl[(sp * 512 + qw) * 16 + g * 4 + j] = lsum[j];
    }
  }
}

// ---------------------------------------------------------------------------
// Kernel 3b: merge 4 split partials. UNCHANGED from R5 (passed).
// ---------------------------------------------------------------------------
__global__ __launch_bounds__(64) void attn_merge_kernel(
    const float* __restrict__ pacc, const float* __restrict__ pm, const float* __restrict__ pl,
    float* __restrict__ out)
{
  const int qw = blockIdx.x;
  const int b = qw >> 7, q0 = (qw & 127) * 16;
  const int lane = threadIdx.x;

#pragma unroll 1
  for (int row = 0; row < 16; ++row) {
    float m0 = pm[(0 * 512 + qw) * 16 + row], m1 = pm[(1 * 512 + qw) * 16 + row];
    float m2 = pm[(2 * 512 + qw) * 16 + row], m3 = pm[(3 * 512 + qw) * 16 + row];
    float M = fmaxf(fmaxf(m0, m1), fmaxf(m2, m3));
    float w0 = __expf(m0 - M), w1 = __expf(m1 - M), w2 = __expf(m2 - M), w3 = __expf(m3 - M);
    float L = w0 * pl[(0 * 512 + qw) * 16 + row] + w1 * pl[(1 * 512 + qw) * 16 + row] +
              w2 * pl[(2 * 512 + qw) * 16 + row] + w3 * pl[(3 * 512 + qw) * 16 + row];
    float v = w0 * pacc[((size_t)(0 * 512 + qw) * 16 + row) * 64 + lane] +
              w1 * pacc[((size_t)(1 * 512 + qw) * 16 + row) * 64 + lane] +
              w2 * pacc[((size_t)(2 * 512 + qw) * 16 + row) * 64 + lane] +
              w3 * pacc[((size_t)(3 * 512 + qw) * 16 + row) * 64 + lane];
    out[(size_t)(b * S_ + q0 + row) * DK_ + lane] = v / L;
  }
}

// ---------------------------------------------------------------------------
// Kernel 3 (fallback if ws too small): R3/R4 verified single-pass attention.
// ---------------------------------------------------------------------------
__global__ __launch_bounds__(64) void attn_kernel(
    const unsigned short* __restrict__ Qp, const unsigned short* __restrict__ Kp,
    const unsigned short* __restrict__ Vt, const unsigned int* __restrict__ mp,
    float* __restrict__ out)
{
  const int lane = threadIdx.x;
  const int g = lane >> 4, r16 = lane & 15;
  const int qt = blockIdx.x & 127;
  const int b  = blockIdx.x >> 7;
  const int q0 = qt * 16;

  __shared__ __align__(16) unsigned short Kt[64][72];
  __shared__ __align__(16) unsigned short Vs[64][72];
  __shared__ __align__(16) unsigned short Pq[16][72];

  short8 aq0, aq1;
  {
    const unsigned short* qrow = Qp + (size_t)(b * S_ + q0 + r16) * DK_ + g * 8;
    aq0 = *reinterpret_cast<const short8*>(qrow);
    aq1 = *reinterpret_cast<const short8*>(qrow + 32);
  }

  float mrun[4], lsum[4], corr[4];
  f32x4 acc[4];
#pragma unroll
  for (int j = 0; j < 4; ++j) { mrun[j] = -3.0e38f; lsum[j] = 0.f; }
#pragma unroll
  for (int nf = 0; nf < 4; ++nf) { acc[nf].x = 0.f; acc[nf].y = 0.f; acc[nf].z = 0.f; acc[nf].w = 0.f; }

  const int srow_stage = lane >> 3, sgran = lane & 7;

  for (int st = 0; st < 32; ++st) {
    const int s0 = st * 64;
#pragma unroll
    for (int i = 0; i < 8; ++i) {
      int r = i * 8 + srow_stage;
      uint4v kv = *reinterpret_cast<const uint4v*>(Kp + (size_t)(b * S_ + s0 + r) * DK_ + sgran * 8);
      *reinterpret_cast<uint4v*>(&Kt[r][sgran * 8]) = kv;
      uint4v vv = *reinterpret_cast<const uint4v*>(Vt + (size_t)(b * DK_ + r) * S_ + s0 + sgran * 8);
      *reinterpret_cast<uint4v*>(&Vs[r][sgran * 8]) = vv;
    }
    unsigned long long mw[4];
#pragma unroll
    for (int j = 0; j < 4; ++j) {
      size_t widx = ((size_t)(b * S_ + q0 + g * 4 + j) * S_ + s0) >> 5;
      mw[j] = *reinterpret_cast<const unsigned long long*>(mp + widx);
    }
    __syncthreads();

    f32x4 sc[4];
#pragma unroll
    for (int nf = 0; nf < 4; ++nf) { sc[nf].x = 0.f; sc[nf].y = 0.f; sc[nf].z = 0.f; sc[nf].w = 0.f; }
#pragma unroll
    for (int nf = 0; nf < 4; ++nf) {
      short8 bk0 = *reinterpret_cast<const short8*>(&Kt[nf * 16 + r16][g * 8]);
      short8 bk1 = *reinterpret_cast<const short8*>(&Kt[nf * 16 + r16][32 + g * 8]);
      sc[nf] = __builtin_amdgcn_mfma_f32_16x16x32_bf16(aq0, bk0, sc[nf], 0, 0, 0);
      sc[nf] = __builtin_amdgcn_mfma_f32_16x16x32_bf16(aq1, bk1, sc[nf], 0, 0, 0);
    }
#pragma unroll
    for (int nf = 0; nf < 4; ++nf)
#pragma unroll
      for (int j = 0; j < 4; ++j) {
        float v = sc[nf][j] * SCALE_;
        sc[nf][j] = ((mw[j] >> (nf * 16 + r16)) & 1ull) ? 1e-9f : v;
      }
#pragma unroll
    for (int j = 0; j < 4; ++j) {
      float tm = fmaxf(fmaxf(sc[0][j], sc[1][j]), fmaxf(sc[2][j], sc[3][j]));
#pragma unroll
      for (int off = 1; off < 16; off <<= 1) tm = fmaxf(tm, __shfl_xor(tm, off));
      float mn = fmaxf(mrun[j], tm);
      corr[j] = __expf(mrun[j] - mn);
      mrun[j] = mn;
    }
#pragma unroll
    for (int nf = 0; nf < 4; ++nf)
#pragma unroll
      for (int j = 0; j < 4; ++j)
        sc[nf][j] = __expf(sc[nf][j] - mrun[j]);
#pragma unroll
    for (int j = 0; j < 4; ++j) {
      float rs = (sc[0][j] + sc[1][j]) + (sc[2][j] + sc[3][j]);
#pragma unroll
      for (int off = 1; off < 16; off <<= 1) rs += __shfl_xor(rs, off);
      lsum[j] = lsum[j] * corr[j] + rs;
    }
#pragma unroll
    for (int nf = 0; nf < 4; ++nf) {
      acc[nf].x *= corr[0]; acc[nf].y *= corr[1]; acc[nf].z *= corr[2]; acc[nf].w *= corr[3];
    }
#pragma unroll
    for (int nf = 0; nf < 4; ++nf)
#pragma unroll
      for (int j = 0; j < 4; ++j)
        Pq[g * 4 + j][nf * 16 + r16] = f2bf(sc[nf][j]);
    asm volatile("s_waitcnt lgkmcnt(0)" ::: "memory");

#pragma unroll
    for (int k2 = 0; k2 < 2; ++k2) {
      short8 pa = *reinterpret_cast<const short8*>(&Pq[r16][k2 * 32 + g * 8]);
#pragma unroll
      for (int nf = 0; nf < 4; ++nf) {
        short8 bv = *reinterpret_cast<const short8*>(&Vs[nf * 16 + r16][k2 * 32 + g * 8]);
        acc[nf] = __builtin_amdgcn_mfma_f32_16x16x32_bf16(pa, bv, acc[nf], 0, 0, 0);
      }
    }
    __syncthreads();
  }

#pragma unroll
  for (int nf = 0; nf < 4; ++nf)
#pragma unroll
    for (int j = 0; j < 4; ++j)
      out[(size_t)(b * S_ + q0 + g * 4 + j) * DK_ + nf * 16 + r16] = acc[nf][j] / lsum[j];
}

// ---------------------------------------------------------------------------
extern "C" void kernel_launch(void* const* d_in, const int* in_sizes, int n_in,
                              void* d_out, int out_size, void* d_ws, size_t ws_size,
                              hipStream_t stream) {
  const float* q  = (const float*)d_in[0];
  const float* k  = (const float*)d_in[1];
  const float* v  = (const float*)d_in[2];
  const void*  mk = d_in[3];
  const float* wq = (const float*)d_in[4];
  const float* wk = (const float*)d_in[5];
  const float* wv = (const float*)d_in[6];

  char* ws = (char*)d_ws;
  unsigned short* Qp   = (unsigned short*)(ws);                         // 1 MB
  unsigned short* Kp   = (unsigned short*)(ws + (1u << 20));            // 1 MB
  unsigned short* Vt   = (unsigned short*)(ws + (2u << 20));            // 1 MB  [b][dk][s]
  unsigned int*   mp   = (unsigned int*)  (ws + (3u << 20));            // 2 MB packed mask
  unsigned int*   flag = (unsigned int*)  (ws + (5u << 20));            // 4 B
  unsigned short* Wb   = (unsigned short*)(ws + (5u << 20) + 4096);     // 384 KB bf16 weights
  float*          pacc = (float*)(ws + (6u << 20));                     // 8 MB partial acc
  float*          pm   = (float*)(ws + (14u << 20));                    // 128 KB partial m
  float*          pl   = (float*)(ws + (14u << 20) + (1u << 17));       // 128 KB partial l

  wconv_kernel<<<96, 256, 0, stream>>>(wq, wk, wv, Wb);
  detect_kernel<<<1, 64, 0, stream>>>((const unsigned int*)mk, flag);
  maskpack_kernel<<<2048, 256, 0, stream>>>((const unsigned char*)mk, (const unsigned int*)mk, flag, mp);
  proj4_kernel<<<dim3(128, 3), 256, 0, stream>>>(q, k, v, Wb, Qp, Kp, Vt);

  if (ws_size >= (15u << 20)) {
    attn_part_kernel<<<2048, 64, 0, stream>>>(Qp, Kp, Vt, mp, pacc, pm, pl);
    attn_merge_kernel<<<512, 64, 0, stream>>>(pacc, pm, pl, (float*)d_out);
  } else {
    attn_kernel<<<512, 64, 0, stream>>>(Qp, Kp, Vt, mp, (float*)d_out);
  }
}

// Round 8
// 86.163 us; speedup vs baseline: 1.4496x; 1.0093x over previous
//
#include <hip/hip_runtime.h>

// Problem constants
#define B_    4
#define S_    2048
#define DM_   1024
#define DK_   64
#define SCALE_ 0.03125f   // 1024^-0.5  (reference scales by d_model^-0.5, not d_k)

typedef float        f32x4  __attribute__((ext_vector_type(4)));
typedef float        float8 __attribute__((ext_vector_type(8)));
typedef short        short8 __attribute__((ext_vector_type(8)));
typedef float        fltx4  __attribute__((ext_vector_type(4)));
typedef unsigned int uint2v __attribute__((ext_vector_type(2)));
typedef unsigned int uint4v __attribute__((ext_vector_type(4)));

// async global->LDS DMA, 16 B per lane. LDS dest is WAVE-UNIFORM base
// (hardware adds lane*16); global src is per-lane.
#define GLL16(gsrc, ldst)                                                   \
  __builtin_amdgcn_global_load_lds(                                         \
      (const __attribute__((address_space(1))) void*)(gsrc),                \
      (__attribute__((address_space(3))) void*)(ldst), 16, 0, 0)

// fp32 -> bf16, round-to-nearest-even
static __device__ __forceinline__ unsigned short f2bf(float f) {
  unsigned u = __float_as_uint(f);
  u += 0x7fffu + ((u >> 16) & 1u);
  return (unsigned short)(u >> 16);
}
static __device__ __forceinline__ uint2v pack4(float a, float b, float c, float d) {
  uint2v r;
  r.x = (unsigned)f2bf(a) | ((unsigned)f2bf(b) << 16);
  r.y = (unsigned)f2bf(c) | ((unsigned)f2bf(d) << 16);
  return r;
}

// ---------------------------------------------------------------------------
// Kernel 0: detect mask element width (int32 of {0,1} vs byte-packed bools).
// ---------------------------------------------------------------------------
__global__ void detect_kernel(const unsigned int* __restrict__ m, unsigned int* __restrict__ flag) {
  unsigned v = m[threadIdx.x];
  unsigned long long bad = __ballot(v > 1u);
  if (threadIdx.x == 0) flag[0] = (bad != 0ull) ? 1u : 0u;
}

// ---------------------------------------------------------------------------
// Kernel W: convert the 3 weight matrices to bf16 once. Wb: [which][64][1024].
// ---------------------------------------------------------------------------
__global__ __launch_bounds__(256) void wconv_kernel(
    const float* __restrict__ wq, const float* __restrict__ wk, const float* __restrict__ wv,
    unsigned short* __restrict__ Wb)
{
  const int idx   = blockIdx.x * 256 + threadIdx.x;
  const int which = idx >> 13;
  const int e     = idx & 8191;
  const float* __restrict__ w = (which == 0) ? wq : (which == 1) ? wk : wv;
  fltx4 v0 = *reinterpret_cast<const fltx4*>(w + (size_t)e * 8);
  fltx4 v1 = *reinterpret_cast<const fltx4*>(w + (size_t)e * 8 + 4);
  uint4v o;
  o.x = (unsigned)f2bf(v0.x) | ((unsigned)f2bf(v0.y) << 16);
  o.y = (unsigned)f2bf(v0.z) | ((unsigned)f2bf(v0.w) << 16);
  o.z = (unsigned)f2bf(v1.x) | ((unsigned)f2bf(v1.y) << 16);
  o.w = (unsigned)f2bf(v1.z) | ((unsigned)f2bf(v1.w) << 16);
  *reinterpret_cast<uint4v*>(Wb + (size_t)which * 65536 + (size_t)e * 8) = o;
}

// ---------------------------------------------------------------------------
// Kernel 1: pack mask to 1 bit/element (2 MB, L2-hot). Verified R2-T3.
// ---------------------------------------------------------------------------
__global__ __launch_bounds__(256) void maskpack_kernel(const unsigned char* __restrict__ mb,
                                                       const unsigned int* __restrict__ mi,
                                                       const unsigned int* __restrict__ flag,
                                                       unsigned int* __restrict__ mp) {
  const int w = blockIdx.x * 256 + threadIdx.x;
  unsigned out = 0;
  if (flag[0]) {
    const uint4v* p = reinterpret_cast<const uint4v*>(mb + (size_t)w * 32);
    uint4v a = p[0], b = p[1];
    unsigned ws0[8];
    ws0[0]=a.x; ws0[1]=a.y; ws0[2]=a.z; ws0[3]=a.w; ws0[4]=b.x; ws0[5]=b.y; ws0[6]=b.z; ws0[7]=b.w;
#pragma unroll
    for (int i = 0; i < 8; ++i) {
      unsigned v = ws0[i];
      out |= ((v & 0x000000ffu) ? 1u : 0u) << (i * 4 + 0);
      out |= ((v & 0x0000ff00u) ? 1u : 0u) << (i * 4 + 1);
      out |= ((v & 0x00ff0000u) ? 1u : 0u) << (i * 4 + 2);
      out |= ((v & 0xff000000u) ? 1u : 0u) << (i * 4 + 3);
    }
  } else {
    const uint4v* p = reinterpret_cast<const uint4v*>(mi + (size_t)w * 32);
#pragma unroll
    for (int i = 0; i < 8; ++i) {
      uint4v a = p[i];
      out |= (a.x ? 1u : 0u) << (i * 4 + 0);
      out |= (a.y ? 1u : 0u) << (i * 4 + 1);
      out |= (a.z ? 1u : 0u) << (i * 4 + 2);
      out |= (a.w ? 1u : 0u) << (i * 4 + 3);
    }
  }
  mp[w] = out;
}

// ---------------------------------------------------------------------------
// Kernel 2 (v6): single-buffered staged projection, HIGH OCCUPANCY.
// Sync structure = proj4 (R6-verified: STAGE -> sync -> MFMA -> sync);
// parameters changed only: 32-row x K=128 tiles, 128 threads (2 waves),
// LDS 32 KB -> 768 blocks = 3 blocks/CU (vs proj4's 1.5) so other blocks'
// stage/compute overlap each block's barrier-drain stall.
// Swizzle maps = proj5's (validated by R7 first-pass): involution applied to
// global SOURCE at stage time and to LDS reads; LDS linear for DMA dest.
// Wave wid owns rows [wid*16, wid*16+16); D[m=g*4+j][n=nf*16+r16] (T1 layout).
// ---------------------------------------------------------------------------
__global__ __launch_bounds__(128) void proj6_kernel(
    const float* __restrict__ xq, const float* __restrict__ xk, const float* __restrict__ xv,
    const unsigned short* __restrict__ Wb,
    unsigned short* __restrict__ Qp, unsigned short* __restrict__ Kp, unsigned short* __restrict__ Vt)
{
  const int which = blockIdx.y;
  const float* __restrict__ x = (which == 0) ? xq : (which == 1) ? xk : xv;
  const unsigned short* __restrict__ wsrc = Wb + (size_t)which * 65536;
  const int row0 = blockIdx.x * 32;
  const int tid = threadIdx.x, wid = tid >> 6;
  const int lane = tid & 63, g = lane >> 4, r16 = lane & 15;

  __shared__ __align__(16) float          XsF[4096];   // 32x128 f32 (swizzled content)
  __shared__ __align__(16) unsigned short WsH[8192];   // 64x128 bf16 (swizzled content)

  f32x4 acc[4];
#pragma unroll
  for (int i = 0; i < 4; ++i) { acc[i].x = 0.f; acc[i].y = 0.f; acc[i].z = 0.f; acc[i].w = 0.f; }

  // inverse-swizzled source coordinates for this thread's DMA slots
  int xrow[8], xcol[8], wrow[8], wcol[8];
#pragma unroll
  for (int i = 0; i < 8; ++i) {
    int L  = i * 2048 + tid * 16;             // linear LDS byte this DMA writes
    int Ux = L ^ (((L >> 9) & 15) << 4);      // X: row pitch 512 B (32 rows)
    xrow[i] = Ux >> 9;  xcol[i] = (Ux & 511) >> 2;
    int Uw = L ^ (((L >> 8) & 15) << 4);      // W: row pitch 256 B (64 rows)
    wrow[i] = Uw >> 8;  wcol[i] = (Uw & 255) >> 1;
  }

  for (int kb = 0; kb < 8; ++kb) {
    const int k0 = kb * 128;
    // stage X: 8 DMA slots (16 KB total across both waves)
#pragma unroll
    for (int i = 0; i < 8; ++i)
      GLL16(x + (size_t)(row0 + xrow[i]) * DM_ + k0 + xcol[i],
            (char*)XsF + i * 2048 + wid * 1024);
    // stage W: 8 DMA slots (16 KB)
#pragma unroll
    for (int i = 0; i < 8; ++i)
      GLL16(wsrc + (size_t)wrow[i] * DM_ + k0 + wcol[i],
            (char*)WsH + i * 2048 + wid * 1024);
    __syncthreads();   // drains vmcnt(0): staged data visible (R6-verified structure)

#pragma unroll
    for (int k2 = 0; k2 < 4; ++k2) {
      const int la  = (wid * 16 + r16) * 512 + k2 * 128 + g * 32;
      const int pa0 = la ^ (r16 << 4);
      const int pa1 = (la + 16) ^ (r16 << 4);
      fltx4 a0 = *reinterpret_cast<const fltx4*>((const char*)XsF + pa0);
      fltx4 a1 = *reinterpret_cast<const fltx4*>((const char*)XsF + pa1);
      short8 a;
      a[0] = (short)f2bf(a0.x); a[1] = (short)f2bf(a0.y);
      a[2] = (short)f2bf(a0.z); a[3] = (short)f2bf(a0.w);
      a[4] = (short)f2bf(a1.x); a[5] = (short)f2bf(a1.y);
      a[6] = (short)f2bf(a1.z); a[7] = (short)f2bf(a1.w);
#pragma unroll
      for (int nf = 0; nf < 4; ++nf) {
        const int lb = (nf * 16 + r16) * 256 + k2 * 64 + g * 16;
        const int pb = lb ^ (r16 << 4);
        short8 b = *reinterpret_cast<const short8*>((const char*)WsH + pb);
        acc[nf] = __builtin_amdgcn_mfma_f32_16x16x32_bf16(a, b, acc[nf], 0, 0, 0);
      }
    }
    __syncthreads();   // all waves done reading before next stage overwrites
  }

  // store: row = row0 + wid*16 + g*4 + j, n = nf*16 + r16
  if (which < 2) {
    unsigned short* __restrict__ dst = (which == 0) ? Qp : Kp;
#pragma unroll
    for (int nf = 0; nf < 4; ++nf)
#pragma unroll
      for (int j = 0; j < 4; ++j)
        dst[(size_t)(row0 + wid * 16 + g * 4 + j) * DK_ + nf * 16 + r16] = f2bf(acc[nf][j]);
  } else {
    const int grow = row0 + wid * 16 + g * 4;
    const int bb = grow >> 11, sin = grow & 2047;
#pragma unroll
    for (int nf = 0; nf < 4; ++nf)
      *reinterpret_cast<uint2v*>(Vt + (size_t)(bb * DK_ + nf * 16 + r16) * S_ + sin) =
          pack4(acc[nf][0], acc[nf][1], acc[nf][2], acc[nf][3]);
  }
}

// ---------------------------------------------------------------------------
// Kernel 3a: flash attention PARTIAL (split-S x4). UNCHANGED (verified R5/R6).
// ---------------------------------------------------------------------------
__global__ __launch_bounds__(64) void attn_part_kernel(
    const unsigned short* __restrict__ Qp, const unsigned short* __restrict__ Kp,
    const unsigned short* __restrict__ Vt, const unsigned int* __restrict__ mp,
    float* __restrict__ pacc, float* __restrict__ pm, float* __restrict__ pl)
{
  const int lane = threadIdx.x;
  const int g = lane >> 4, r16 = lane & 15;
  const int bx = blockIdx.x;
  const int sp = bx >> 9;
  const int qw = bx & 511;
  const int b  = qw >> 7;
  const int q0 = (qw & 127) * 16;

  __shared__ __align__(16) unsigned short Kt[64][72];
  __shared__ __align__(16) unsigned short Vs[64][72];
  __shared__ __align__(16) unsigned short Pq[16][72];

  short8 aq0, aq1;
  {
    const unsigned short* qrow = Qp + (size_t)(b * S_ + q0 + r16) * DK_ + g * 8;
    aq0 = *reinterpret_cast<const short8*>(qrow);
    aq1 = *reinterpret_cast<const short8*>(qrow + 32);
  }

  float mrun[4], lsum[4], corr[4];
  f32x4 acc[4];
#pragma unroll
  for (int j = 0; j < 4; ++j) { mrun[j] = -3.0e38f; lsum[j] = 0.f; }
#pragma unroll
  for (int nf = 0; nf < 4; ++nf) { acc[nf].x = 0.f; acc[nf].y = 0.f; acc[nf].z = 0.f; acc[nf].w = 0.f; }

  const int srow_stage = lane >> 3, sgran = lane & 7;

  for (int st = sp * 8; st < sp * 8 + 8; ++st) {
    const int s0 = st * 64;
#pragma unroll
    for (int i = 0; i < 8; ++i) {
      int r = i * 8 + srow_stage;
      uint4v kv = *reinterpret_cast<const uint4v*>(Kp + (size_t)(b * S_ + s0 + r) * DK_ + sgran * 8);
      *reinterpret_cast<uint4v*>(&Kt[r][sgran * 8]) = kv;
      uint4v vv = *reinterpret_cast<const uint4v*>(Vt + (size_t)(b * DK_ + r) * S_ + s0 + sgran * 8);
      *reinterpret_cast<uint4v*>(&Vs[r][sgran * 8]) = vv;
    }
    unsigned long long mw[4];
#pragma unroll
    for (int j = 0; j < 4; ++j) {
      size_t widx = ((size_t)(b * S_ + q0 + g * 4 + j) * S_ + s0) >> 5;
      mw[j] = *reinterpret_cast<const unsigned long long*>(mp + widx);
    }
    __syncthreads();

    f32x4 sc[4];
#pragma unroll
    for (int nf = 0; nf < 4; ++nf) { sc[nf].x = 0.f; sc[nf].y = 0.f; sc[nf].z = 0.f; sc[nf].w = 0.f; }
#pragma unroll
    for (int nf = 0; nf < 4; ++nf) {
      short8 bk0 = *reinterpret_cast<const short8*>(&Kt[nf * 16 + r16][g * 8]);
      short8 bk1 = *reinterpret_cast<const short8*>(&Kt[nf * 16 + r16][32 + g * 8]);
      sc[nf] = __builtin_amdgcn_mfma_f32_16x16x32_bf16(aq0, bk0, sc[nf], 0, 0, 0);
      sc[nf] = __builtin_amdgcn_mfma_f32_16x16x32_bf16(aq1, bk1, sc[nf], 0, 0, 0);
    }
#pragma unroll
    for (int nf = 0; nf < 4; ++nf)
#pragma unroll
      for (int j = 0; j < 4; ++j) {
        float v = sc[nf][j] * SCALE_;
        sc[nf][j] = ((mw[j] >> (nf * 16 + r16)) & 1ull) ? 1e-9f : v;
      }
#pragma unroll
    for (int j = 0; j < 4; ++j) {
      float tm = fmaxf(fmaxf(sc[0][j], sc[1][j]), fmaxf(sc[2][j], sc[3][j]));
#pragma unroll
      for (int off = 1; off < 16; off <<= 1) tm = fmaxf(tm, __shfl_xor(tm, off));
      float mn = fmaxf(mrun[j], tm);
      corr[j] = __expf(mrun[j] - mn);
      mrun[j] = mn;
    }
#pragma unroll
    for (int nf = 0; nf < 4; ++nf)
#pragma unroll
      for (int j = 0; j < 4; ++j)
        sc[nf][j] = __expf(sc[nf][j] - mrun[j]);
#pragma unroll
    for (int j = 0; j < 4; ++j) {
      float rs = (sc[0][j] + sc[1][j]) + (sc[2][j] + sc[3][j]);
#pragma unroll
      for (int off = 1; off < 16; off <<= 1) rs += __shfl_xor(rs, off);
      lsum[j] = lsum[j] * corr[j] + rs;
    }
#pragma unroll
    for (int nf = 0; nf < 4; ++nf) {
      acc[nf].x *= corr[0]; acc[nf].y *= corr[1]; acc[nf].z *= corr[2]; acc[nf].w *= corr[3];
    }
#pragma unroll
    for (int nf = 0; nf < 4; ++nf)
#pragma unroll
      for (int j = 0; j < 4; ++j)
        Pq[g * 4 + j][nf * 16 + r16] = f2bf(sc[nf][j]);
    asm volatile("s_waitcnt lgkmcnt(0)" ::: "memory");

#pragma unroll
    for (int k2 = 0; k2 < 2; ++k2) {
      short8 pa = *reinterpret_cast<const short8*>(&Pq[r16][k2 * 32 + g * 8]);
#pragma unroll
      for (int nf = 0; nf < 4; ++nf) {
        short8 bv = *reinterpret_cast<const short8*>(&Vs[nf * 16 + r16][k2 * 32 + g * 8]);
        acc[nf] = __builtin_amdgcn_mfma_f32_16x16x32_bf16(pa, bv, acc[nf], 0, 0, 0);
      }
    }
    __syncthreads();
  }

  float* __restrict__ pa = pacc + (size_t)(sp * 512 + qw) * 1024;
#pragma unroll
  for (int nf = 0; nf < 4; ++nf)
#pragma unroll
    for (int j = 0; j < 4; ++j)
      pa[(g * 4 + j) * 64 + nf * 16 + r16] = acc[nf][j];
  if (r16 == 0) {
#pragma unroll
    for (int j = 0; j < 4; ++j) {
      pm[(sp * 512 + qw) * 16 + g * 4 + j] = mrun[j];
      pl[(sp * 512 + qw) * 16 + g * 4 + j] = lsum[j];
    }
  }
}

// ---------------------------------------------------------------------------
// Kernel 3b: merge 4 split partials. UNCHANGED (verified R5/R6).
// ---------------------------------------------------------------------------
__global__ __launch_bounds__(64) void attn_merge_kernel(
    const float* __restrict__ pacc, const float* __restrict__ pm, const float* __restrict__ pl,
    float* __restrict__ out)
{
  const int qw = blockIdx.x;
  const int b = qw >> 7, q0 = (qw & 127) * 16;
  const int lane = threadIdx.x;

#pragma unroll 1
  for (int row = 0; row < 16; ++row) {
    float m0 = pm[(0 * 512 + qw) * 16 + row], m1 = pm[(1 * 512 + qw) * 16 + row];
    float m2 = pm[(2 * 512 + qw) * 16 + row], m3 = pm[(3 * 512 + qw) * 16 + row];
    float M = fmaxf(fmaxf(m0, m1), fmaxf(m2, m3));
    float w0 = __expf(m0 - M), w1 = __expf(m1 - M), w2 = __expf(m2 - M), w3 = __expf(m3 - M);
    float L = w0 * pl[(0 * 512 + qw) * 16 + row] + w1 * pl[(1 * 512 + qw) * 16 + row] +
              w2 * pl[(2 * 512 + qw) * 16 + row] + w3 * pl[(3 * 512 + qw) * 16 + row];
    float v = w0 * pacc[((size_t)(0 * 512 + qw) * 16 + row) * 64 + lane] +
              w1 * pacc[((size_t)(1 * 512 + qw) * 16 + row) * 64 + lane] +
              w2 * pacc[((size_t)(2 * 512 + qw) * 16 + row) * 64 + lane] +
              w3 * pacc[((size_t)(3 * 512 + qw) * 16 + row) * 64 + lane];
    out[(size_t)(b * S_ + q0 + row) * DK_ + lane] = v / L;
  }
}

// ---------------------------------------------------------------------------
// Kernel 3 (fallback if ws too small): verified single-pass attention.
// ---------------------------------------------------------------------------
__global__ __launch_bounds__(64) void attn_kernel(
    const unsigned short* __restrict__ Qp, const unsigned short* __restrict__ Kp,
    const unsigned short* __restrict__ Vt, const unsigned int* __restrict__ mp,
    float* __restrict__ out)
{
  const int lane = threadIdx.x;
  const int g = lane >> 4, r16 = lane & 15;
  const int qt = blockIdx.x & 127;
  const int b  = blockIdx.x >> 7;
  const int q0 = qt * 16;

  __shared__ __align__(16) unsigned short Kt[64][72];
  __shared__ __align__(16) unsigned short Vs[64][72];
  __shared__ __align__(16) unsigned short Pq[16][72];

  short8 aq0, aq1;
  {
    const unsigned short* qrow = Qp + (size_t)(b * S_ + q0 + r16) * DK_ + g * 8;
    aq0 = *reinterpret_cast<const short8*>(qrow);
    aq1 = *reinterpret_cast<const short8*>(qrow + 32);
  }

  float mrun[4], lsum[4], corr[4];
  f32x4 acc[4];
#pragma unroll
  for (int j = 0; j < 4; ++j) { mrun[j] = -3.0e38f; lsum[j] = 0.f; }
#pragma unroll
  for (int nf = 0; nf < 4; ++nf) { acc[nf].x = 0.f; acc[nf].y = 0.f; acc[nf].z = 0.f; acc[nf].w = 0.f; }

  const int srow_stage = lane >> 3, sgran = lane & 7;

  for (int st = 0; st < 32; ++st) {
    const int s0 = st * 64;
#pragma unroll
    for (int i = 0; i < 8; ++i) {
      int r = i * 8 + srow_stage;
      uint4v kv = *reinterpret_cast<const uint4v*>(Kp + (size_t)(b * S_ + s0 + r) * DK_ + sgran * 8);
      *reinterpret_cast<uint4v*>(&Kt[r][sgran * 8]) = kv;
      uint4v vv = *reinterpret_cast<const uint4v*>(Vt + (size_t)(b * DK_ + r) * S_ + s0 + sgran * 8);
      *reinterpret_cast<uint4v*>(&Vs[r][sgran * 8]) = vv;
    }
    unsigned long long mw[4];
#pragma unroll
    for (int j = 0; j < 4; ++j) {
      size_t widx = ((size_t)(b * S_ + q0 + g * 4 + j) * S_ + s0) >> 5;
      mw[j] = *reinterpret_cast<const unsigned long long*>(mp + widx);
    }
    __syncthreads();

    f32x4 sc[4];
#pragma unroll
    for (int nf = 0; nf < 4; ++nf) { sc[nf].x = 0.f; sc[nf].y = 0.f; sc[nf].z = 0.f; sc[nf].w = 0.f; }
#pragma unroll
    for (int nf = 0; nf < 4; ++nf) {
      short8 bk0 = *reinterpret_cast<const short8*>(&Kt[nf * 16 + r16][g * 8]);
      short8 bk1 = *reinterpret_cast<const short8*>(&Kt[nf * 16 + r16][32 + g * 8]);
      sc[nf] = __builtin_amdgcn_mfma_f32_16x16x32_bf16(aq0, bk0, sc[nf], 0, 0, 0);
      sc[nf] = __builtin_amdgcn_mfma_f32_16x16x32_bf16(aq1, bk1, sc[nf], 0, 0, 0);
    }
#pragma unroll
    for (int nf = 0; nf < 4; ++nf)
#pragma unroll
      for (int j = 0; j < 4; ++j) {
        float v = sc[nf][j] * SCALE_;
        sc[nf][j] = ((mw[j] >> (nf * 16 + r16)) & 1ull) ? 1e-9f : v;
      }
#pragma unroll
    for (int j = 0; j < 4; ++j) {
      float tm = fmaxf(fmaxf(sc[0][j], sc[1][j]), fmaxf(sc[2][j], sc[3][j]));
#pragma unroll
      for (int off = 1; off < 16; off <<= 1) tm = fmaxf(tm, __shfl_xor(tm, off));
      float mn = fmaxf(mrun[j], tm);
      corr[j] = __expf(mrun[j] - mn);
      mrun[j] = mn;
    }
#pragma unroll
    for (int nf = 0; nf < 4; ++nf)
#pragma unroll
      for (int j = 0; j < 4; ++j)
        sc[nf][j] = __expf(sc[nf][j] - mrun[j]);
#pragma unroll
    for (int j = 0; j < 4; ++j) {
      float rs = (sc[0][j] + sc[1][j]) + (sc[2][j] + sc[3][j]);
#pragma unroll
      for (int off = 1; off < 16; off <<= 1) rs += __shfl_xor(rs, off);
      lsum[j] = lsum[j] * corr[j] + rs;
    }
#pragma unroll
    for (int nf = 0; nf < 4; ++nf) {
      acc[nf].x *= corr[0]; acc[nf].y *= corr[1]; acc[nf].z *= corr[2]; acc[nf].w *= corr[3];
    }
#pragma unroll
    for (int nf = 0; nf < 4; ++nf)
#pragma unroll
      for (int j = 0; j < 4; ++j)
        Pq[g * 4 + j][nf * 16 + r16] = f2bf(sc[nf][j]);
    asm volatile("s_waitcnt lgkmcnt(0)" ::: "memory");

#pragma unroll
    for (int k2 = 0; k2 < 2; ++k2) {
      short8 pa = *reinterpret_cast<const short8*>(&Pq[r16][k2 * 32 + g * 8]);
#pragma unroll
      for (int nf = 0; nf < 4; ++nf) {
        short8 bv = *reinterpret_cast<const short8*>(&Vs[nf * 16 + r16][k2 * 32 + g * 8]);
        acc[nf] = __builtin_amdgcn_mfma_f32_16x16x32_bf16(pa, bv, acc[nf], 0, 0, 0);
      }
    }
    __syncthreads();
  }

#pragma unroll
  for (int nf = 0; nf < 4; ++nf)
#pragma unroll
    for (int j = 0; j < 4; ++j)
      out[(size_t)(b * S_ + q0 + g * 4 + j) * DK_ + nf * 16 + r16] = acc[nf][j] / lsum[j];
}

// ---------------------------------------------------------------------------
extern "C" void kernel_launch(void* const* d_in, const int* in_sizes, int n_in,
                              void* d_out, int out_size, void* d_ws, size_t ws_size,
                              hipStream_t stream) {
  const float* q  = (const float*)d_in[0];
  const float* k  = (const float*)d_in[1];
  const float* v  = (const float*)d_in[2];
  const void*  mk = d_in[3];
  const float* wq = (const float*)d_in[4];
  const float* wk = (const float*)d_in[5];
  const float* wv = (const float*)d_in[6];

  char* ws = (char*)d_ws;
  unsigned short* Qp   = (unsigned short*)(ws);                         // 1 MB
  unsigned short* Kp   = (unsigned short*)(ws + (1u << 20));            // 1 MB
  unsigned short* Vt   = (unsigned short*)(ws + (2u << 20));            // 1 MB  [b][dk][s]
  unsigned int*   mp   = (unsigned int*)  (ws + (3u << 20));            // 2 MB packed mask
  unsigned int*   flag = (unsigned int*)  (ws + (5u << 20));            // 4 B
  unsigned short* Wb   = (unsigned short*)(ws + (5u << 20) + 4096);     // 384 KB bf16 weights
  float*          pacc = (float*)(ws + (6u << 20));                     // 8 MB partial acc
  float*          pm   = (float*)(ws + (14u << 20));                    // 128 KB partial m
  float*          pl   = (float*)(ws + (14u << 20) + (1u << 17));       // 128 KB partial l

  wconv_kernel<<<96, 256, 0, stream>>>(wq, wk, wv, Wb);
  detect_kernel<<<1, 64, 0, stream>>>((const unsigned int*)mk, flag);
  maskpack_kernel<<<2048, 256, 0, stream>>>((const unsigned char*)mk, (const unsigned int*)mk, flag, mp);
  proj6_kernel<<<dim3(256, 3), 128, 0, stream>>>(q, k, v, Wb, Qp, Kp, Vt);

  if (ws_size >= (15u << 20)) {
    attn_part_kernel<<<2048, 64, 0, stream>>>(Qp, Kp, Vt, mp, pacc, pm, pl);
    attn_merge_kernel<<<512, 64, 0, stream>>>(pacc, pm, pl, (float*)d_out);
  } else {
    attn_kernel<<<512, 64, 0, stream>>>(Qp, Kp, Vt, mp, (float*)d_out);
  }
}